// Round 5
// baseline (410.950 us; speedup 1.0000x reference)
//
#include <hip/hip_runtime.h>

#define BN_TOT 24576   // B*N
#define NPTS 786432    // BN_TOT*32
#define EPS_ 1e-5f
#define NBLK 2048
#define TOTW (NBLK * 4)   // fallback path: 8192 waves
#define NB2 1024          // big-ws path: 4 blocks/CU resident when VGPR<=128
#define TOTW2 (NB2 * 4)   // 4096 waves
#define NIT2 (BN_TOT / TOTW2)  // 6 iterations per wave, exact

typedef float v4f __attribute__((ext_vector_type(4)));
typedef __attribute__((ext_vector_type(8))) short sv8;    // 8 bf16 (4 VGPRs)
typedef __attribute__((ext_vector_type(4))) float fv4;    // MFMA acc
typedef unsigned short u16;
typedef unsigned int u32;

__device__ __forceinline__ v4f ld4(const float* p) { return *(const v4f*)p; }
__device__ __forceinline__ void st4(float* p, v4f v) { *(v4f*)p = v; }

__device__ __forceinline__ float bf2f(u16 u) {
    union { u32 i; float f; } v; v.i = ((u32)u) << 16; return v.f;
}
__device__ __forceinline__ u32 pack2bf(float a, float b) {   // lo=a, hi=b, RNE
    union { float f; u32 i; } x, y; x.f = a; y.f = b;
    u32 xr = x.i + 0x7FFFu + ((x.i >> 16) & 1u);
    u32 yr = y.i + 0x7FFFu + ((y.i >> 16) & 1u);
    return (xr >> 16) | (yr & 0xFFFF0000u);
}

// Workspace S (floats):
// [128..191] sum2 [192..255] sumsq2 [256..319] sum3 [320..383] sumsq3 [384] cnt (fallback)
// [400..444] M (x xT upper-tri 45) [445..453] sum_x (9) [454] cnt_raw
// [512+L*128 ..] scaleL/shiftL (fallback path only)
// H16 at byte offset 8192, ~100.7 MB, MFMA-NATIVE layout (u16 units per 2048-elem record):
//   value(ch, p) at  (ch>>4)*512 + (p>>4)*256 + ((ch>>2)&3)*64 + (p&15)*4 + (ch&3)
//   writer lane(quad,n) stores uint2 at mt*512 + nt*256 + lane*4 — 512B/wave contiguous.

__global__ void k_finalize(const float* __restrict__ g, const float* __restrict__ b,
                           float* __restrict__ S, int layer) {
    int c = threadIdx.x;
    if (c < 64) {
        float cnt = fmaxf(S[384], 1.f);
        float mean = S[layer * 128 + c] / cnt;
        float var = fmaxf(S[layer * 128 + 64 + c] / cnt - mean * mean, 0.f);
        float sc = g[c] * rsqrtf(var + EPS_);
        float sh = b[c] - mean * sc;
        S[512 + layer * 128 + c] = sc;
        S[512 + layer * 128 + 64 + c] = sh;
    }
}

// ---- moment-based stage-1 stats (R13-proven) -------------------------------
__global__ __launch_bounds__(256) void k_mom(const float* __restrict__ poly,
                                             const int* __restrict__ mask,
                                             float* __restrict__ S) {
    __shared__ float red[4][55];
    const int t = threadIdx.x, wv = t >> 6, lane = t & 63;
    float M[45], sx[9], cc = 0.f;
    #pragma unroll
    for (int i = 0; i < 45; i++) M[i] = 0.f;
    #pragma unroll
    for (int i = 0; i < 9; i++) sx[i] = 0.f;
    for (int idx = blockIdx.x * 256 + t; idx < NPTS; idx += NBLK * 256) {
        float m = (mask[idx] != 0) ? 1.f : 0.f;
        const float* xp = poly + (size_t)idx * 9;
        float x[9];
        #pragma unroll
        for (int j = 0; j < 9; j++) x[j] = xp[j];
        cc += m;
        int k = 0;
        #pragma unroll
        for (int a = 0; a < 9; a++) {
            float xa = x[a] * m;
            sx[a] += xa;
            #pragma unroll
            for (int b2 = a; b2 < 9; b2++) { M[k] += xa * x[b2]; k++; }
        }
    }
    #pragma unroll
    for (int i = 0; i < 45; i++) {
        float v = M[i];
        v += __shfl_xor(v, 1); v += __shfl_xor(v, 2); v += __shfl_xor(v, 4);
        v += __shfl_xor(v, 8); v += __shfl_xor(v, 16); v += __shfl_xor(v, 32);
        M[i] = v;
    }
    #pragma unroll
    for (int i = 0; i < 9; i++) {
        float v = sx[i];
        v += __shfl_xor(v, 1); v += __shfl_xor(v, 2); v += __shfl_xor(v, 4);
        v += __shfl_xor(v, 8); v += __shfl_xor(v, 16); v += __shfl_xor(v, 32);
        sx[i] = v;
    }
    {
        float v = cc;
        v += __shfl_xor(v, 1); v += __shfl_xor(v, 2); v += __shfl_xor(v, 4);
        v += __shfl_xor(v, 8); v += __shfl_xor(v, 16); v += __shfl_xor(v, 32);
        cc = v;
    }
    if (lane == 0) {
        #pragma unroll
        for (int i = 0; i < 45; i++) red[wv][i] = M[i];
        #pragma unroll
        for (int i = 0; i < 9; i++) red[wv][45 + i] = sx[i];
        red[wv][54] = cc;
    }
    __syncthreads();
    if (t < 55) atomicAdd(&S[400 + t], red[0][t] + red[1][t] + red[2][t] + red[3][t]);
}

__global__ void k_finalize_mom(const float* __restrict__ Wpre,
                               const float* __restrict__ g, const float* __restrict__ b,
                               float* __restrict__ S) {
    int c = threadIdx.x;
    if (c < 64) {
        float w[9];
        #pragma unroll
        for (int j = 0; j < 9; j++) w[j] = Wpre[c * 9 + j];
        float cnt = fmaxf(S[454], 1.f);
        float s1 = 0.f;
        #pragma unroll
        for (int j = 0; j < 9; j++) s1 += w[j] * S[445 + j];
        float s2 = 0.f;
        int k = 0;
        #pragma unroll
        for (int a = 0; a < 9; a++)
            #pragma unroll
            for (int b2 = a; b2 < 9; b2++) {
                float mm = S[400 + k];
                s2 += (a == b2) ? w[a] * w[a] * mm : 2.f * w[a] * w[b2] * mm;
                k++;
            }
        float mean = s1 / cnt;
        float var = fmaxf(s2 / cnt - mean * mean, 0.f);
        float sc = g[c] * rsqrtf(var + EPS_);
        float sh = b[c] - mean * sc;
        S[512 + c] = sc;
        S[576 + c] = sh;
        if (c == 0) S[384] = S[454];
    }
}

// ---- shared helpers --------------------------------------------------------
__device__ __forceinline__ void mm_acc(float a[4][8], v4f av, v4f w0, v4f w1) {
    #pragma unroll
    for (int i = 0; i < 4; i++) {
        #pragma unroll
        for (int j = 0; j < 4; j++) {
            a[i][j] += av[i] * w0[j];
            a[i][4 + j] += av[i] * w1[j];
        }
    }
}

__device__ __forceinline__ void tzero(float a[4][8]) {
    #pragma unroll
    for (int i = 0; i < 4; i++)
        #pragma unroll
        for (int j = 0; j < 8; j++) a[i][j] = 0.f;
}

__device__ __forceinline__ void load_x(const float* xg, float* xTw, int lane) {
    for (int e = lane; e < 288; e += 64) {
        float v = xg[e];
        int p = e / 9, c = e - 9 * p;
        xTw[c * 36 + p] = v;
    }
}

__device__ __forceinline__ void stage1(const float* xTw, const float* WpT,
                                       int pg, int cg, float a1[4][8]) {
    tzero(a1);
    #pragma unroll
    for (int k = 0; k < 9; k++) {
        v4f av = ld4(xTw + k * 36 + 4 * pg);
        v4f w0 = ld4(WpT + k * 64 + 8 * cg);
        v4f w1 = ld4(WpT + k * 64 + 8 * cg + 4);
        mm_acc(a1, av, w0, w1);
    }
}

__device__ __forceinline__ void gemv64(const float* actw, const float* WT,
                                       int pg, int cg, float a[4][8]) {
    #pragma unroll 8
    for (int k = 0; k < 64; k++) {
        v4f av = ld4(actw + k * 32 + 4 * (pg ^ (k >> 3)));
        v4f w0 = ld4(WT + k * 64 + 8 * cg);
        v4f w1 = ld4(WT + k * 64 + 8 * cg + 4);
        mm_acc(a, av, w0, w1);
    }
}

__device__ __forceinline__ void bn_store_act(float* actw, const float a[4][8],
                                             const float* sc, const float* sh,
                                             const float m[4], int pg, int cg,
                                             float f[4][8]) {
    #pragma unroll
    for (int j = 0; j < 8; j++) {
        v4f v;
        #pragma unroll
        for (int i = 0; i < 4; i++) {
            float x = fmaxf(a[i][j] * sc[j] + sh[j], 0.f) * m[i];
            v[i] = x; f[i][j] = x;
        }
        st4(actw + (8 * cg + j) * 32 + 4 * (pg ^ cg), v);
    }
}

__device__ __forceinline__ void pool_reduce(const float f[4][8], float pmax[8]) {
    #pragma unroll
    for (int j = 0; j < 8; j++) {
        float v = fmaxf(fmaxf(f[0][j], f[1][j]), fmaxf(f[2][j], f[3][j]));
        v = fmaxf(v, __shfl_xor(v, 8));
        v = fmaxf(v, __shfl_xor(v, 16));
        v = fmaxf(v, __shfl_xor(v, 32));
        pmax[j] = v;
    }
}

__device__ __forceinline__ void qa_glob(const float pmax[8], const float* W1,
                                        float* pbufw, int pg, int cg, float qa[8]) {
    if (pg == 0)
        #pragma unroll
        for (int j = 0; j < 8; j++) pbufw[8 * cg + j] = pmax[j];
    __builtin_amdgcn_wave_barrier();
    #pragma unroll
    for (int j = 0; j < 8; j++) qa[j] = 0.f;
    #pragma unroll 4
    for (int kk = 0; kk < 16; kk++) {
        float p0 = pbufw[4 * kk], p1 = pbufw[4 * kk + 1];
        float p2 = pbufw[4 * kk + 2], p3 = pbufw[4 * kk + 3];
        #pragma unroll
        for (int j = 0; j < 8; j++) {
            v4f w = ld4(W1 + (8 * cg + j) * 128 + 64 + 4 * kk);
            qa[j] += w[0] * p0 + w[1] * p1 + w[2] * p2 + w[3] * p3;
        }
    }
}

__device__ __forceinline__ void stats_acc(const float a[4][8], const float m[4],
                                          float sp[8], float ssp[8]) {
    #pragma unroll
    for (int i = 0; i < 4; i++)
        #pragma unroll
        for (int j = 0; j < 8; j++) {
            float hv = a[i][j] * m[i];
            sp[j] += hv; ssp[j] += hv * a[i][j];
        }
}

__device__ __forceinline__ void stats_flush(float sp[8], float ssp[8],
                                            float (*red_s)[64], float (*red_ss)[64],
                                            float* S, int base, int t, int wv,
                                            int pg, int cg) {
    #pragma unroll
    for (int j = 0; j < 8; j++) {
        float v = sp[j];
        v += __shfl_xor(v, 8); v += __shfl_xor(v, 16); v += __shfl_xor(v, 32);
        sp[j] = v;
        float w = ssp[j];
        w += __shfl_xor(w, 8); w += __shfl_xor(w, 16); w += __shfl_xor(w, 32);
        ssp[j] = w;
    }
    if (pg == 0)
        #pragma unroll
        for (int j = 0; j < 8; j++) { red_s[wv][8 * cg + j] = sp[j]; red_ss[wv][8 * cg + j] = ssp[j]; }
    __syncthreads();
    if (t < 64) {
        atomicAdd(&S[base + t], red_s[0][t] + red_s[1][t] + red_s[2][t] + red_s[3][t]);
        atomicAdd(&S[base + 64 + t], red_ss[0][t] + red_ss[1][t] + red_ss[2][t] + red_ss[3][t]);
    }
}

// ---- pass 2 (big ws): MFMA stage2, W1-frags in LDS, SW-pipelined (R2-proven)
// Stage2 MFMA: A=W1 (K=128), B=[feat;pooled]. Stage1 VALU in B-layout.
// Layouts (HW-validated): A[m=lane&15][k=quad*8+j], B[k=quad*8+j][n=lane&15],
// C: col(n)=lane&15, row(m)=mt*16+quad*4+r.
__global__ __launch_bounds__(256) void k_stats2_mfma(const float* __restrict__ poly,
                                                     const int* __restrict__ mask,
                                                     const float* __restrict__ Wpre,
                                                     const float* __restrict__ gpre,
                                                     const float* __restrict__ bpre,
                                                     const float* __restrict__ W1,
                                                     float* __restrict__ S,
                                                     u16* __restrict__ H16) {
    __shared__ __align__(16) float WpT[576];
    __shared__ __align__(16) float xT[4][324];
    __shared__ float scsh[128];
    __shared__ float red_s[4][64], red_ss[4][64];
    __shared__ __align__(16) uint4 awl[16 * 64];   // 16KB: W1 A-frags, lane-ordered
    const int t = threadIdx.x, wv = t >> 6, lane = t & 63;
    const int n = lane & 15, quad = lane >> 4;
    for (int i = t; i < 576; i += 256) { int c = i >> 6, ch = i & 63; WpT[i] = Wpre[ch * 9 + c]; }

    // inline BN1 finalize from moments (cold preamble)
    if (t < 64) {
        float w[9];
        #pragma unroll
        for (int j = 0; j < 9; j++) w[j] = Wpre[t * 9 + j];
        float cnt = fmaxf(S[454], 1.f);
        float s1 = 0.f;
        #pragma unroll
        for (int j = 0; j < 9; j++) s1 += w[j] * S[445 + j];
        float s2 = 0.f;
        int k = 0;
        #pragma unroll
        for (int a = 0; a < 9; a++)
            #pragma unroll
            for (int b2 = a; b2 < 9; b2++) {
                float mm = S[400 + k];
                s2 += (a == b2) ? w[a] * w[a] * mm : 2.f * w[a] * w[b2] * mm;
                k++;
            }
        float mean = s1 / cnt;
        float var = fmaxf(s2 / cnt - mean * mean, 0.f);
        float sc = gpre[t] * rsqrtf(var + EPS_);
        scsh[t] = sc;
        scsh[64 + t] = bpre[t] - mean * sc;
    }

    // build shared A-fragment table: wave wv packs mt=wv (frag depends only on lane)
    #pragma unroll
    for (int ss = 0; ss < 4; ss++) {
        const float* wr = W1 + (size_t)(wv * 16 + n) * 128 + ss * 32 + quad * 8;
        union { uint4 q; u32 w[4]; } uu;
        #pragma unroll
        for (int d = 0; d < 4; d++) uu.w[d] = pack2bf(wr[2 * d], wr[2 * d + 1]);
        awl[(wv * 4 + ss) * 64 + lane] = uu.q;
    }
    __syncthreads();
    float sck[16], shk[16];
    #pragma unroll
    for (int s = 0; s < 2; s++)
        #pragma unroll
        for (int j = 0; j < 8; j++) {
            int c = s * 32 + quad * 8 + j;
            sck[s * 8 + j] = scsh[c];
            shk[s * 8 + j] = scsh[64 + c];
        }

    float sp16[16], ssp16[16];
    #pragma unroll
    for (int e = 0; e < 16; e++) { sp16[e] = 0.f; ssp16[e] = 0.f; }

    // loop-invariant transpose-scatter addresses (e/9 hoisted out of the loop)
    int ax0, ax1, ax2, ax3, ax4;
    {
        int e = lane;        int p = e / 9; ax0 = (e - 9 * p) * 36 + p;
        e = lane + 64;       p = e / 9;     ax1 = (e - 9 * p) * 36 + p;
        e = lane + 128;      p = e / 9;     ax2 = (e - 9 * p) * 36 + p;
        e = lane + 192;      p = e / 9;     ax3 = (e - 9 * p) * 36 + p;
        e = lane + 256;      p = e / 9;     ax4 = (e - 9 * p) * 36 + p;
    }

    const sv8* awp = (const sv8*)awl;
    const int wgid = blockIdx.x * 4 + wv;
    // prologue prefetch: polyline wgid
    float xr0, xr1, xr2, xr3, xr4, mvr;
    {
        const float* xg = poly + (size_t)wgid * 288;
        xr0 = xg[lane]; xr1 = xg[lane + 64]; xr2 = xg[lane + 128]; xr3 = xg[lane + 192];
        xr4 = (lane < 32) ? xg[256 + lane] : 0.f;
        mvr = (lane < 32 && mask[wgid * 32 + lane] != 0) ? 1.f : 0.f;
    }

    for (int it = 0; it < NIT2; it++) {
        const int bn = wgid + it * TOTW2;
        const float mv = mvr;
        // scatter prefetched x into per-wave LDS tile
        xT[wv][ax0] = xr0; xT[wv][ax1] = xr1; xT[wv][ax2] = xr2; xT[wv][ax3] = xr3;
        if (lane < 32) xT[wv][ax4] = xr4;
        __builtin_amdgcn_wave_barrier();
        // issue next polyline's loads; latency hides under this iteration's compute
        if (it < NIT2 - 1) {
            const int bnn = bn + TOTW2;
            const float* xg = poly + (size_t)bnn * 288;
            xr0 = xg[lane]; xr1 = xg[lane + 64]; xr2 = xg[lane + 128]; xr3 = xg[lane + 192];
            if (lane < 32) {
                xr4 = xg[256 + lane];
                mvr = (mask[bnn * 32 + lane] != 0) ? 1.f : 0.f;
            }
        }
        // stage1 (VALU) for points {n, 16+n}, channels {s*32+quad*8+j}
        float f0[16], f1[16];
        #pragma unroll
        for (int e = 0; e < 16; e++) { f0[e] = 0.f; f1[e] = 0.f; }
        #pragma unroll
        for (int k = 0; k < 9; k++) {
            float x0 = xT[wv][k * 36 + n];
            float x1 = xT[wv][k * 36 + 16 + n];
            v4f wA0 = ld4(WpT + k * 64 + quad * 8);
            v4f wA1 = ld4(WpT + k * 64 + quad * 8 + 4);
            v4f wB0 = ld4(WpT + k * 64 + 32 + quad * 8);
            v4f wB1 = ld4(WpT + k * 64 + 32 + quad * 8 + 4);
            #pragma unroll
            for (int j = 0; j < 4; j++) {
                f0[j] += x0 * wA0[j];  f0[4 + j] += x0 * wA1[j];
                f0[8 + j] += x0 * wB0[j]; f0[12 + j] += x0 * wB1[j];
                f1[j] += x1 * wA0[j];  f1[4 + j] += x1 * wA1[j];
                f1[8 + j] += x1 * wB0[j]; f1[12 + j] += x1 * wB1[j];
            }
        }
        float mp0 = __shfl(mv, n), mp1 = __shfl(mv, 16 + n);
        #pragma unroll
        for (int e = 0; e < 16; e++) {
            f0[e] = fmaxf(f0[e] * sck[e] + shk[e], 0.f) * mp0;
            f1[e] = fmaxf(f1[e] * sck[e] + shk[e], 0.f) * mp1;
        }
        float pm[16];
        #pragma unroll
        for (int e = 0; e < 16; e++) {
            float v = fmaxf(f0[e], f1[e]);
            v = fmaxf(v, __shfl_xor(v, 1));
            v = fmaxf(v, __shfl_xor(v, 2));
            v = fmaxf(v, __shfl_xor(v, 4));
            v = fmaxf(v, __shfl_xor(v, 8));
            pm[e] = v;
        }
        sv8 bg0[2], bg1[2], bp[2];
        #pragma unroll
        for (int s = 0; s < 2; s++) {
            union { sv8 v; u32 w[4]; } a, b, c;
            #pragma unroll
            for (int d = 0; d < 4; d++) {
                a.w[d] = pack2bf(f0[s * 8 + 2 * d], f0[s * 8 + 2 * d + 1]);
                b.w[d] = pack2bf(f1[s * 8 + 2 * d], f1[s * 8 + 2 * d + 1]);
                c.w[d] = pack2bf(pm[s * 8 + 2 * d], pm[s * 8 + 2 * d + 1]);
            }
            bg0[s] = a.v; bg1[s] = b.v; bp[s] = c.v;
        }
        // per-mt MFMA: A-frags from LDS (short-lived), acc dies after stats+store
        u16* Hw = H16 + (size_t)bn * 2048;
        #pragma unroll
        for (int mt = 0; mt < 4; mt++) {
            sv8 a0 = awp[(mt * 4 + 0) * 64 + lane];
            sv8 a1 = awp[(mt * 4 + 1) * 64 + lane];
            sv8 a2 = awp[(mt * 4 + 2) * 64 + lane];
            sv8 a3 = awp[(mt * 4 + 3) * 64 + lane];
            fv4 c0 = {0.f, 0.f, 0.f, 0.f}, c1 = {0.f, 0.f, 0.f, 0.f};
            c0 = __builtin_amdgcn_mfma_f32_16x16x32_bf16(a0, bg0[0], c0, 0, 0, 0);
            c0 = __builtin_amdgcn_mfma_f32_16x16x32_bf16(a1, bg0[1], c0, 0, 0, 0);
            c0 = __builtin_amdgcn_mfma_f32_16x16x32_bf16(a2, bp[0], c0, 0, 0, 0);
            c0 = __builtin_amdgcn_mfma_f32_16x16x32_bf16(a3, bp[1], c0, 0, 0, 0);
            c1 = __builtin_amdgcn_mfma_f32_16x16x32_bf16(a0, bg1[0], c1, 0, 0, 0);
            c1 = __builtin_amdgcn_mfma_f32_16x16x32_bf16(a1, bg1[1], c1, 0, 0, 0);
            c1 = __builtin_amdgcn_mfma_f32_16x16x32_bf16(a2, bp[0], c1, 0, 0, 0);
            c1 = __builtin_amdgcn_mfma_f32_16x16x32_bf16(a3, bp[1], c1, 0, 0, 0);
            #pragma unroll
            for (int r = 0; r < 4; r++) {
                sp16[mt * 4 + r] += c0[r] * mp0 + c1[r] * mp1;
                ssp16[mt * 4 + r] += c0[r] * c0[r] * mp0 + c1[r] * c1[r] * mp1;
            }
            uint2 pk0, pk1;
            pk0.x = pack2bf(c0[0], c0[1]); pk0.y = pack2bf(c0[2], c0[3]);
            pk1.x = pack2bf(c1[0], c1[1]); pk1.y = pack2bf(c1[2], c1[3]);
            *(uint2*)(Hw + mt * 512 + lane * 4) = pk0;
            *(uint2*)(Hw + mt * 512 + 256 + lane * 4) = pk1;
        }
        __builtin_amdgcn_wave_barrier();
    }
    #pragma unroll
    for (int e = 0; e < 16; e++) {
        float v = sp16[e];
        v += __shfl_xor(v, 1); v += __shfl_xor(v, 2); v += __shfl_xor(v, 4); v += __shfl_xor(v, 8);
        sp16[e] = v;
        float w = ssp16[e];
        w += __shfl_xor(w, 1); w += __shfl_xor(w, 2); w += __shfl_xor(w, 4); w += __shfl_xor(w, 8);
        ssp16[e] = w;
    }
    if (n == 0) {
        #pragma unroll
        for (int mt = 0; mt < 4; mt++)
            #pragma unroll
            for (int r = 0; r < 4; r++) {
                red_s[wv][mt * 16 + quad * 4 + r] = sp16[mt * 4 + r];
                red_ss[wv][mt * 16 + quad * 4 + r] = ssp16[mt * 4 + r];
            }
    }
    __syncthreads();
    if (t < 64) {
        atomicAdd(&S[128 + t], red_s[0][t] + red_s[1][t] + red_s[2][t] + red_s[3][t]);
        atomicAdd(&S[128 + 64 + t], red_ss[0][t] + red_ss[1][t] + red_ss[2][t] + red_ss[3][t]);
    }
}

// ---- pass 3 (big ws): MFMA-native H16 in/out, W2-frags in LDS --------------
__global__ __launch_bounds__(256) void k_stats3_mfma(const int* __restrict__ mask,
                                                     const float* __restrict__ g1,
                                                     const float* __restrict__ b1,
                                                     const float* __restrict__ W2,
                                                     float* __restrict__ S,
                                                     u16* __restrict__ H16) {
    __shared__ float scsh[128];
    __shared__ float red_s[4][64], red_ss[4][64];
    __shared__ __align__(16) uint4 awl[8 * 64];   // 8KB: W2 A-frags, lane-ordered
    const int t = threadIdx.x, wv = t >> 6, lane = t & 63;
    const int n = lane & 15, quad = lane >> 4;

    if (t < 64) {
        float cnt = fmaxf(S[454], 1.f);
        float mean = S[128 + t] / cnt;
        float var = fmaxf(S[192 + t] / cnt - mean * mean, 0.f);
        float sc = g1[t] * rsqrtf(var + EPS_);
        scsh[t] = sc;
        scsh[64 + t] = b1[t] - mean * sc;
    }

    #pragma unroll
    for (int s = 0; s < 2; s++) {
        const float* wr = W2 + (wv * 16 + n) * 64 + s * 32 + quad * 8;
        union { uint4 q; u32 w[4]; } uu;
        #pragma unroll
        for (int d = 0; d < 4; d++) uu.w[d] = pack2bf(wr[2 * d], wr[2 * d + 1]);
        awl[(wv * 2 + s) * 64 + lane] = uu.q;
    }
    __syncthreads();
    float sck[16], shk[16];
    #pragma unroll
    for (int s = 0; s < 2; s++)
        #pragma unroll
        for (int j = 0; j < 8; j++) {
            int k = s * 32 + quad * 8 + j;
            sck[s * 8 + j] = scsh[k];
            shk[s * 8 + j] = scsh[64 + k];
        }

    float sp16[16], ssp16[16];
    #pragma unroll
    for (int e = 0; e < 16; e++) { sp16[e] = 0.f; ssp16[e] = 0.f; }

    const sv8* awp = (const sv8*)awl;
    const int wgid = blockIdx.x * 4 + wv;
    // reader offset for B-fragment gather: ch = s*32+quad*8+j ->
    //   mt' = s*2+(quad>>1), quad'_base = (quad&1)*2 (+ j>>2), r = j&3
    const int hoff = (quad >> 1) * 512 + (quad & 1) * 128 + n * 4;
    uint2 hr[2][2][2];   // [nt][s][half]
    float mvr;
    {
        const u16* Hb = H16 + (size_t)wgid * 2048;
        #pragma unroll
        for (int nt = 0; nt < 2; nt++)
            #pragma unroll
            for (int s = 0; s < 2; s++)
                #pragma unroll
                for (int h = 0; h < 2; h++)
                    hr[nt][s][h] = *(const uint2*)(Hb + hoff + s * 1024 + nt * 256 + h * 64);
        mvr = (lane < 32 && mask[wgid * 32 + lane] != 0) ? 1.f : 0.f;
    }

    for (int it = 0; it < NIT2; it++) {
        const int bn = wgid + it * TOTW2;
        const float mv = mvr;
        float mpn[2] = {__shfl(mv, n), __shfl(mv, 16 + n)};
        sv8 bg[2][2];
        #pragma unroll
        for (int nt = 0; nt < 2; nt++)
            #pragma unroll
            for (int s = 0; s < 2; s++) {
                u32 ws[4] = {hr[nt][s][0].x, hr[nt][s][0].y, hr[nt][s][1].x, hr[nt][s][1].y};
                union { sv8 v; u32 w[4]; } uu;
                #pragma unroll
                for (int d = 0; d < 4; d++) {
                    union { u32 u; float f; } lo, hi;
                    lo.u = ws[d] << 16; hi.u = ws[d] & 0xFFFF0000u;
                    float g0 = fmaxf(lo.f * sck[s * 8 + 2 * d] + shk[s * 8 + 2 * d], 0.f) * mpn[nt];
                    float g1v = fmaxf(hi.f * sck[s * 8 + 2 * d + 1] + shk[s * 8 + 2 * d + 1], 0.f) * mpn[nt];
                    uu.w[d] = pack2bf(g0, g1v);
                }
                bg[nt][s] = uu.v;
            }
        // prefetch next polyline's h1 fragments (hr fully consumed above)
        if (it < NIT2 - 1) {
            const int bnn = bn + TOTW2;
            const u16* Hb = H16 + (size_t)bnn * 2048;
            #pragma unroll
            for (int nt = 0; nt < 2; nt++)
                #pragma unroll
                for (int s = 0; s < 2; s++)
                    #pragma unroll
                    for (int h = 0; h < 2; h++)
                        hr[nt][s][h] = *(const uint2*)(Hb + hoff + s * 1024 + nt * 256 + h * 64);
            if (lane < 32) mvr = (mask[bnn * 32 + lane] != 0) ? 1.f : 0.f;
        }
        u16* Hw = H16 + (size_t)bn * 2048;
        #pragma unroll
        for (int nt = 0; nt < 2; nt++) {
            float mp = mpn[nt];
            #pragma unroll
            for (int mt = 0; mt < 4; mt++) {
                sv8 a0 = awp[(mt * 2 + 0) * 64 + lane];
                sv8 a1 = awp[(mt * 2 + 1) * 64 + lane];
                fv4 c = {0.f, 0.f, 0.f, 0.f};
                c = __builtin_amdgcn_mfma_f32_16x16x32_bf16(a0, bg[nt][0], c, 0, 0, 0);
                c = __builtin_amdgcn_mfma_f32_16x16x32_bf16(a1, bg[nt][1], c, 0, 0, 0);
                #pragma unroll
                for (int r = 0; r < 4; r++) {
                    sp16[mt * 4 + r] += c[r] * mp;
                    ssp16[mt * 4 + r] += c[r] * c[r] * mp;
                }
                uint2 pk;
                pk.x = pack2bf(c[0], c[1]);
                pk.y = pack2bf(c[2], c[3]);
                *(uint2*)(Hw + mt * 512 + nt * 256 + lane * 4) = pk;
            }
        }
    }
    #pragma unroll
    for (int e = 0; e < 16; e++) {
        float v = sp16[e];
        v += __shfl_xor(v, 1); v += __shfl_xor(v, 2); v += __shfl_xor(v, 4); v += __shfl_xor(v, 8);
        sp16[e] = v;
        float w = ssp16[e];
        w += __shfl_xor(w, 1); w += __shfl_xor(w, 2); w += __shfl_xor(w, 4); w += __shfl_xor(w, 8);
        ssp16[e] = w;
    }
    if (n == 0) {
        #pragma unroll
        for (int mt = 0; mt < 4; mt++)
            #pragma unroll
            for (int r = 0; r < 4; r++) {
                red_s[wv][mt * 16 + quad * 4 + r] = sp16[mt * 4 + r];
                red_ss[wv][mt * 16 + quad * 4 + r] = ssp16[mt * 4 + r];
            }
    }
    __syncthreads();
    if (t < 64) {
        atomicAdd(&S[256 + t], red_s[0][t] + red_s[1][t] + red_s[2][t] + red_s[3][t]);
        atomicAdd(&S[256 + 64 + t], red_ss[0][t] + red_ss[1][t] + red_ss[2][t] + red_ss[3][t]);
    }
}

// ---- pass 4 (big ws): MFMA-native H16 read, Wo1/Wo2 from global, tiny LDS --
__global__ __launch_bounds__(256) void k_out_load(const int* __restrict__ mask,
                                                  const float* __restrict__ g2,
                                                  const float* __restrict__ b2,
                                                  const float* __restrict__ Wo1,
                                                  const float* __restrict__ bo1,
                                                  const float* __restrict__ Wo2,
                                                  const float* __restrict__ bo2,
                                                  const float* __restrict__ S,
                                                  const u16* __restrict__ H16,
                                                  float* __restrict__ out) {
    __shared__ float pbuf[4][64];
    __shared__ float scsh[128];
    const int t = threadIdx.x, wv = t >> 6, lane = t & 63;
    const int n = lane & 15, quad = lane >> 4;
    if (t < 64) {
        float cnt = fmaxf(S[454], 1.f);
        float mean = S[256 + t] / cnt;
        float var = fmaxf(S[320 + t] / cnt - mean * mean, 0.f);
        float sc = g2[t] * rsqrtf(var + EPS_);
        scsh[t] = sc;
        scsh[64 + t] = b2[t] - mean * sc;
    }
    __syncthreads();
    float sc3[16], sh3[16];
    #pragma unroll
    for (int mt = 0; mt < 4; mt++)
        #pragma unroll
        for (int r = 0; r < 4; r++) {
            sc3[mt * 4 + r] = scsh[mt * 16 + quad * 4 + r];
            sh3[mt * 4 + r] = scsh[64 + mt * 16 + quad * 4 + r];
        }
    float bo1v = bo1[lane], bo2a = bo2[lane], bo2b = bo2[64 + lane];
    const int wgid = blockIdx.x * 4 + wv;
    uint2 hr[4][2];   // [mt][nt]
    float mvr;
    {
        const u16* Hb = H16 + (size_t)wgid * 2048;
        #pragma unroll
        for (int mt = 0; mt < 4; mt++)
            #pragma unroll
            for (int nt = 0; nt < 2; nt++)
                hr[mt][nt] = *(const uint2*)(Hb + mt * 512 + nt * 256 + lane * 4);
        mvr = (lane < 32 && mask[wgid * 32 + lane] != 0) ? 1.f : 0.f;
    }
    for (int it = 0; it < NIT2; it++) {
        const int bn = wgid + it * TOTW2;
        const float mv = mvr;
        float mpn[2] = {__shfl(mv, n), __shfl(mv, 16 + n)};
        float vf = __ballot(mv > 0.5f) ? 1.f : 0.f;
        float pm[16];
        #pragma unroll
        for (int mt = 0; mt < 4; mt++)
            #pragma unroll
            for (int nt = 0; nt < 2; nt++) {
                u32 wx = hr[mt][nt].x, wy = hr[mt][nt].y;
                float v0 = bf2f((u16)(wx & 0xFFFFu)), v1 = bf2f((u16)(wx >> 16));
                float v2 = bf2f((u16)(wy & 0xFFFFu)), v3 = bf2f((u16)(wy >> 16));
                float mp = mpn[nt];
                float e0 = fmaxf(v0 * sc3[mt * 4 + 0] + sh3[mt * 4 + 0], 0.f) * mp;
                float e1 = fmaxf(v1 * sc3[mt * 4 + 1] + sh3[mt * 4 + 1], 0.f) * mp;
                float e2 = fmaxf(v2 * sc3[mt * 4 + 2] + sh3[mt * 4 + 2], 0.f) * mp;
                float e3 = fmaxf(v3 * sc3[mt * 4 + 3] + sh3[mt * 4 + 3], 0.f) * mp;
                if (nt == 0) {
                    pm[mt * 4 + 0] = e0; pm[mt * 4 + 1] = e1;
                    pm[mt * 4 + 2] = e2; pm[mt * 4 + 3] = e3;
                } else {
                    pm[mt * 4 + 0] = fmaxf(pm[mt * 4 + 0], e0);
                    pm[mt * 4 + 1] = fmaxf(pm[mt * 4 + 1], e1);
                    pm[mt * 4 + 2] = fmaxf(pm[mt * 4 + 2], e2);
                    pm[mt * 4 + 3] = fmaxf(pm[mt * 4 + 3], e3);
                }
            }
        if (it < NIT2 - 1) {
            const int bnn = bn + TOTW2;
            const u16* Hb = H16 + (size_t)bnn * 2048;
            #pragma unroll
            for (int mt = 0; mt < 4; mt++)
                #pragma unroll
                for (int nt = 0; nt < 2; nt++)
                    hr[mt][nt] = *(const uint2*)(Hb + mt * 512 + nt * 256 + lane * 4);
            if (lane < 32) mvr = (mask[bnn * 32 + lane] != 0) ? 1.f : 0.f;
        }
        #pragma unroll
        for (int e = 0; e < 16; e++) {
            float v = pm[e];
            v = fmaxf(v, __shfl_xor(v, 1));
            v = fmaxf(v, __shfl_xor(v, 2));
            v = fmaxf(v, __shfl_xor(v, 4));
            v = fmaxf(v, __shfl_xor(v, 8));
            pm[e] = v;
        }
        if (n == 0) {
            #pragma unroll
            for (int mt = 0; mt < 4; mt++)
                #pragma unroll
                for (int r = 0; r < 4; r++)
                    pbuf[wv][mt * 16 + quad * 4 + r] = pm[mt * 4 + r];
        }
        __builtin_amdgcn_wave_barrier();
        float y1 = bo1v;
        #pragma unroll 4
        for (int kk = 0; kk < 16; kk++) {
            v4f w = ld4(Wo1 + lane * 64 + 4 * kk);
            y1 += w[0] * pbuf[wv][4 * kk] + w[1] * pbuf[wv][4 * kk + 1]
                + w[2] * pbuf[wv][4 * kk + 2] + w[3] * pbuf[wv][4 * kk + 3];
        }
        y1 = fmaxf(y1, 0.f);
        pbuf[wv][lane] = y1;
        __builtin_amdgcn_wave_barrier();
        float o0 = bo2a, o1 = bo2b;
        #pragma unroll 4
        for (int kk = 0; kk < 16; kk++) {
            v4f w0 = ld4(Wo2 + lane * 64 + 4 * kk);
            v4f w1 = ld4(Wo2 + (64 + lane) * 64 + 4 * kk);
            float p0 = pbuf[wv][4 * kk], p1 = pbuf[wv][4 * kk + 1];
            float p2 = pbuf[wv][4 * kk + 2], p3 = pbuf[wv][4 * kk + 3];
            o0 += w0[0] * p0 + w0[1] * p1 + w0[2] * p2 + w0[3] * p3;
            o1 += w1[0] * p0 + w1[1] * p1 + w1[2] * p2 + w1[3] * p3;
        }
        out[(size_t)bn * 128 + lane] = o0 * vf;
        out[(size_t)bn * 128 + 64 + lane] = o1 * vf;
        __builtin_amdgcn_wave_barrier();
    }
}

// ---- fallback (small ws): recompute path, untouched ------------------------
__device__ __forceinline__ void qa_lds_fb(const float pmax[8], const float* W1pT,
                                          int cg, float qa[8]) {
    #pragma unroll
    for (int j = 0; j < 8; j++) qa[j] = 0.f;
    #pragma unroll
    for (int k = 0; k < 64; k++) {
        float pv = __shfl(pmax[k & 7], k >> 3);
        v4f w0 = ld4(W1pT + k * 64 + 8 * cg);
        v4f w1 = ld4(W1pT + k * 64 + 8 * cg + 4);
        #pragma unroll
        for (int j = 0; j < 4; j++) { qa[j] += pv * w0[j]; qa[4 + j] += pv * w1[j]; }
    }
}

__global__ __launch_bounds__(256) void k_stats2_fb(const float* __restrict__ poly,
                                                   const int* __restrict__ mask,
                                                   const float* __restrict__ Wpre,
                                                   const float* __restrict__ W1,
                                                   float* __restrict__ S) {
    __shared__ __align__(16) float WpT[576];
    __shared__ __align__(16) float W1aT[4096];
    __shared__ __align__(16) float W1pT[4096];
    __shared__ __align__(16) float act[4][2048];
    __shared__ __align__(16) float xT[4][324];
    __shared__ float red_s[4][64], red_ss[4][64];
    const int t = threadIdx.x, wv = t >> 6, lane = t & 63;
    const int pg = lane >> 3, cg = lane & 7;
    for (int i = t; i < 576; i += 256) { int c = i >> 6, ch = i & 63; WpT[i] = Wpre[ch * 9 + c]; }
    for (int i = t; i < 4096; i += 256) {
        int k = i >> 6, ch = i & 63;
        W1aT[i] = W1[ch * 128 + k];
        W1pT[i] = W1[ch * 128 + 64 + k];
    }
    __syncthreads();
    float sc1[8], sh1[8];
    #pragma unroll
    for (int j = 0; j < 8; j++) { sc1[j] = S[512 + 8 * cg + j]; sh1[j] = S[576 + 8 * cg + j]; }
    float sp[8] = {0}, ssp[8] = {0};
    const int wgid = blockIdx.x * 4 + wv;
    for (int bn = wgid; bn < BN_TOT; bn += TOTW) {
        float mv = (lane < 32 && mask[bn * 32 + lane] != 0) ? 1.f : 0.f;
        float m[4];
        #pragma unroll
        for (int i = 0; i < 4; i++) m[i] = __shfl(mv, 4 * pg + i);
        load_x(poly + (size_t)bn * 288, xT[wv], lane);
        __builtin_amdgcn_wave_barrier();
        float a1[4][8], f[4][8];
        stage1(xT[wv], WpT, pg, cg, a1);
        bn_store_act(act[wv], a1, sc1, sh1, m, pg, cg, f);
        float pmax[8], qa[8];
        pool_reduce(f, pmax);
        qa_lds_fb(pmax, W1pT, cg, qa);
        __builtin_amdgcn_wave_barrier();
        float a2[4][8];
        #pragma unroll
        for (int i = 0; i < 4; i++)
            #pragma unroll
            for (int j = 0; j < 8; j++) a2[i][j] = qa[j];
        gemv64(act[wv], W1aT, pg, cg, a2);
        stats_acc(a2, m, sp, ssp);
        __builtin_amdgcn_wave_barrier();
    }
    stats_flush(sp, ssp, red_s, red_ss, S, 128, t, wv, pg, cg);
}

template<bool DO_OUT>
__global__ __launch_bounds__(256) void k_rec34(const float* __restrict__ poly,
                                               const int* __restrict__ mask,
                                               const float* __restrict__ Wpre,
                                               const float* __restrict__ W1,
                                               const float* __restrict__ W2,
                                               const float* __restrict__ Wo1,
                                               const float* __restrict__ bo1,
                                               const float* __restrict__ Wo2,
                                               const float* __restrict__ bo2,
                                               float* __restrict__ S,
                                               float* __restrict__ out) {
    __shared__ __align__(16) float WpT[576];
    __shared__ __align__(16) float W1aT[4096];
    __shared__ __align__(16) float W2T[4096];
    __shared__ __align__(16) float act[4][2048];
    __shared__ __align__(16) float xT[4][324];
    __shared__ float pbuf[4][64];
    __shared__ float red_s[4][64], red_ss[4][64];
    const int t = threadIdx.x, wv = t >> 6, lane = t & 63;
    const int pg = lane >> 3, cg = lane & 7;
    for (int i = t; i < 576; i += 256) { int c = i >> 6, ch = i & 63; WpT[i] = Wpre[ch * 9 + c]; }
    for (int i = t; i < 4096; i += 256) {
        int k = i >> 6, ch = i & 63;
        W1aT[i] = W1[ch * 128 + k];
        W2T[i] = W2[ch * 64 + k];
    }
    __syncthreads();
    float sc1[8], sh1[8], sc2[8], sh2[8], sc3[8], sh3[8];
    #pragma unroll
    for (int j = 0; j < 8; j++) {
        sc1[j] = S[512 + 8 * cg + j]; sh1[j] = S[576 + 8 * cg + j];
        sc2[j] = S[640 + 8 * cg + j]; sh2[j] = S[704 + 8 * cg + j];
    }
    if constexpr (DO_OUT)
        #pragma unroll
        for (int j = 0; j < 8; j++) { sc3[j] = S[768 + 8 * cg + j]; sh3[j] = S[832 + 8 * cg + j]; }
    float bo1v = 0.f, bo2a = 0.f, bo2b = 0.f;
    if constexpr (DO_OUT) { bo1v = bo1[lane]; bo2a = bo2[lane]; bo2b = bo2[64 + lane]; }
    float sp[8] = {0}, ssp[8] = {0};
    const int wgid = blockIdx.x * 4 + wv;
    for (int bn = wgid; bn < BN_TOT; bn += TOTW) {
        float mv = (lane < 32 && mask[bn * 32 + lane] != 0) ? 1.f : 0.f;
        float m[4];
        #pragma unroll
        for (int i = 0; i < 4; i++) m[i] = __shfl(mv, 4 * pg + i);
        load_x(poly + (size_t)bn * 288, xT[wv], lane);
        __builtin_amdgcn_wave_barrier();
        float a1[4][8], f[4][8];
        stage1(xT[wv], WpT, pg, cg, a1);
        bn_store_act(act[wv], a1, sc1, sh1, m, pg, cg, f);
        float pmax[8], qa[8];
        pool_reduce(f, pmax);
        qa_glob(pmax, W1, pbuf[wv], pg, cg, qa);
        __builtin_amdgcn_wave_barrier();
        float a2[4][8];
        #pragma unroll
        for (int i = 0; i < 4; i++)
            #pragma unroll
            for (int j = 0; j < 8; j++) a2[i][j] = qa[j];
        gemv64(act[wv], W1aT, pg, cg, a2);
        __builtin_amdgcn_wave_barrier();
        bn_store_act(act[wv], a2, sc2, sh2, m, pg, cg, f);
        __builtin_amdgcn_wave_barrier();
        float a3[4][8];
        tzero(a3);
        gemv64(act[wv], W2T, pg, cg, a3);
        if constexpr (!DO_OUT) {
            stats_acc(a3, m, sp, ssp);
        } else {
            float px[8];
            #pragma unroll
            for (int j = 0; j < 8; j++) {
                float v = 0.f;
                #pragma unroll
                for (int i = 0; i < 4; i++)
                    v = fmaxf(v, fmaxf(a3[i][j] * sc3[j] + sh3[j], 0.f) * m[i]);
                px[j] = v;
            }
            #pragma unroll
            for (int j = 0; j < 8; j++) {
                float v = px[j];
                v = fmaxf(v, __shfl_xor(v, 8));
                v = fmaxf(v, __shfl_xor(v, 16));
                v = fmaxf(v, __shfl_xor(v, 32));
                px[j] = v;
            }
            if (pg == 0)
                #pragma unroll
                for (int j = 0; j < 8; j++) pbuf[wv][8 * cg + j] = px[j];
            __builtin_amdgcn_wave_barrier();
            float y1 = bo1v;
            #pragma unroll 4
            for (int kk = 0; kk < 16; kk++) {
                v4f w = ld4(Wo1 + lane * 64 + 4 * kk);
                y1 += w[0] * pbuf[wv][4 * kk] + w[1] * pbuf[wv][4 * kk + 1]
                    + w[2] * pbuf[wv][4 * kk + 2] + w[3] * pbuf[wv][4 * kk + 3];
            }
            y1 = fmaxf(y1, 0.f);
            pbuf[wv][lane] = y1;
            __builtin_amdgcn_wave_barrier();
            float o0 = bo2a, o1 = bo2b;
            #pragma unroll 4
            for (int kk = 0; kk < 16; kk++) {
                v4f w0 = ld4(Wo2 + lane * 64 + 4 * kk);
                v4f w1 = ld4(Wo2 + (64 + lane) * 64 + 4 * kk);
                float p0 = pbuf[wv][4 * kk], p1 = pbuf[wv][4 * kk + 1];
                float p2 = pbuf[wv][4 * kk + 2], p3 = pbuf[wv][4 * kk + 3];
                o0 += w0[0] * p0 + w0[1] * p1 + w0[2] * p2 + w0[3] * p3;
                o1 += w1[0] * p0 + w1[1] * p1 + w1[2] * p2 + w1[3] * p3;
            }
            float vf = __ballot(mv > 0.5f) ? 1.f : 0.f;
            out[(size_t)bn * 128 + lane] = o0 * vf;
            out[(size_t)bn * 128 + 64 + lane] = o1 * vf;
        }
        __builtin_amdgcn_wave_barrier();
    }
    if constexpr (!DO_OUT)
        stats_flush(sp, ssp, red_s, red_ss, S, 256, t, wv, pg, cg);
}

extern "C" void kernel_launch(void* const* d_in, const int* in_sizes, int n_in,
                              void* d_out, int out_size, void* d_ws, size_t ws_size,
                              hipStream_t stream) {
    const float* poly = (const float*)d_in[0];
    const int*   mask = (const int*)d_in[1];
    const float* Wpre = (const float*)d_in[2];
    const float* gpre = (const float*)d_in[3];
    const float* bpre = (const float*)d_in[4];
    const float* W1   = (const float*)d_in[5];
    const float* g1   = (const float*)d_in[6];
    const float* b1   = (const float*)d_in[7];
    const float* W2   = (const float*)d_in[8];
    const float* g2   = (const float*)d_in[9];
    const float* b2   = (const float*)d_in[10];
    const float* Wo1  = (const float*)d_in[11];
    const float* bo1  = (const float*)d_in[12];
    const float* Wo2  = (const float*)d_in[13];
    const float* bo2  = (const float*)d_in[14];

    float* S = (float*)d_ws;
    u16* H16 = (u16*)((char*)d_ws + 8192);
    float* out = (float*)d_out;

    const size_t needWS = 8192 + (size_t)BN_TOT * 2048 * sizeof(u16);  // ~100.7 MB

    hipMemsetAsync(S, 0, 512 * sizeof(float), stream);
    k_mom<<<NBLK, 256, 0, stream>>>(poly, mask, S);
    if (ws_size >= needWS) {
        k_stats2_mfma<<<NB2, 256, 0, stream>>>(poly, mask, Wpre, gpre, bpre, W1, S, H16);
        k_stats3_mfma<<<NB2, 256, 0, stream>>>(mask, g1, b1, W2, S, H16);
        k_out_load<<<NB2, 256, 0, stream>>>(mask, g2, b2, Wo1, bo1, Wo2, bo2, S, H16, out);
    } else {
        k_finalize_mom<<<1, 64, 0, stream>>>(Wpre, gpre, bpre, S);
        k_stats2_fb<<<NBLK, 256, 0, stream>>>(poly, mask, Wpre, W1, S);
        k_finalize<<<1, 64, 0, stream>>>(g1, b1, S, 1);
        k_rec34<false><<<NBLK, 256, 0, stream>>>(poly, mask, Wpre, W1, W2, Wo1, bo1, Wo2, bo2, S, out);
        k_finalize<<<1, 64, 0, stream>>>(g2, b2, S, 2);
        k_rec34<true><<<NBLK, 256, 0, stream>>>(poly, mask, Wpre, W1, W2, Wo1, bo1, Wo2, bo2, S, out);
    }
}

// Round 6
// 340.152 us; speedup vs baseline: 1.2081x; 1.2081x over previous
//
#include <hip/hip_runtime.h>

#define BN_TOT 24576   // B*N
#define NPTS 786432    // BN_TOT*32
#define EPS_ 1e-5f
#define NBLK 2048
#define TOTW (NBLK * 4)   // fallback path: 8192 waves
#define NB2 1024          // big-ws path: 4 blocks/CU resident when VGPR<=128
#define TOTW2 (NB2 * 4)   // 4096 waves
#define NIT2 (BN_TOT / TOTW2)  // 6 iterations per wave, exact
#define NBO 768           // out_load: 3 blocks/CU (49.5KB LDS), all resident
#define TOTWO (NBO * 4)   // 3072 waves
#define NITO (BN_TOT / TOTWO)  // 8 iterations per wave, exact

typedef float v4f __attribute__((ext_vector_type(4)));
typedef __attribute__((ext_vector_type(8))) short sv8;    // 8 bf16 (4 VGPRs)
typedef __attribute__((ext_vector_type(4))) float fv4;    // MFMA acc
typedef unsigned short u16;
typedef unsigned int u32;

__device__ __forceinline__ v4f ld4(const float* p) { return *(const v4f*)p; }
__device__ __forceinline__ void st4(float* p, v4f v) { *(v4f*)p = v; }

__device__ __forceinline__ float bf2f(u16 u) {
    union { u32 i; float f; } v; v.i = ((u32)u) << 16; return v.f;
}
__device__ __forceinline__ u32 pack2bf(float a, float b) {   // lo=a, hi=b, RNE
    union { float f; u32 i; } x, y; x.f = a; y.f = b;
    u32 xr = x.i + 0x7FFFu + ((x.i >> 16) & 1u);
    u32 yr = y.i + 0x7FFFu + ((y.i >> 16) & 1u);
    return (xr >> 16) | (yr & 0xFFFF0000u);
}

// Workspace S (floats):
// [128..191] sum2 [192..255] sumsq2 [256..319] sum3 [320..383] sumsq3 [384] cnt (fallback)
// [400..444] M (x xT upper-tri 45) [445..453] sum_x (9) [454] cnt_raw
// [512+L*128 ..] scaleL/shiftL (fallback path only)
// H16 at byte offset 8192, ~100.7 MB, MFMA-NATIVE layout (u16 units per 2048-elem record):
//   value(ch, p) at  (ch>>4)*512 + (p>>4)*256 + ((ch>>2)&3)*64 + (p&15)*4 + (ch&3)
//   writer lane(quad,n) stores uint2 at mt*512 + nt*256 + lane*4 — 512B/wave contiguous.

__global__ void k_finalize(const float* __restrict__ g, const float* __restrict__ b,
                           float* __restrict__ S, int layer) {
    int c = threadIdx.x;
    if (c < 64) {
        float cnt = fmaxf(S[384], 1.f);
        float mean = S[layer * 128 + c] / cnt;
        float var = fmaxf(S[layer * 128 + 64 + c] / cnt - mean * mean, 0.f);
        float sc = g[c] * rsqrtf(var + EPS_);
        float sh = b[c] - mean * sc;
        S[512 + layer * 128 + c] = sc;
        S[512 + layer * 128 + 64 + c] = sh;
    }
}

// ---- moment-based stage-1 stats (R13-proven) -------------------------------
__global__ __launch_bounds__(256) void k_mom(const float* __restrict__ poly,
                                             const int* __restrict__ mask,
                                             float* __restrict__ S) {
    __shared__ float red[4][55];
    const int t = threadIdx.x, wv = t >> 6, lane = t & 63;
    float M[45], sx[9], cc = 0.f;
    #pragma unroll
    for (int i = 0; i < 45; i++) M[i] = 0.f;
    #pragma unroll
    for (int i = 0; i < 9; i++) sx[i] = 0.f;
    for (int idx = blockIdx.x * 256 + t; idx < NPTS; idx += NBLK * 256) {
        float m = (mask[idx] != 0) ? 1.f : 0.f;
        const float* xp = poly + (size_t)idx * 9;
        float x[9];
        #pragma unroll
        for (int j = 0; j < 9; j++) x[j] = xp[j];
        cc += m;
        int k = 0;
        #pragma unroll
        for (int a = 0; a < 9; a++) {
            float xa = x[a] * m;
            sx[a] += xa;
            #pragma unroll
            for (int b2 = a; b2 < 9; b2++) { M[k] += xa * x[b2]; k++; }
        }
    }
    #pragma unroll
    for (int i = 0; i < 45; i++) {
        float v = M[i];
        v += __shfl_xor(v, 1); v += __shfl_xor(v, 2); v += __shfl_xor(v, 4);
        v += __shfl_xor(v, 8); v += __shfl_xor(v, 16); v += __shfl_xor(v, 32);
        M[i] = v;
    }
    #pragma unroll
    for (int i = 0; i < 9; i++) {
        float v = sx[i];
        v += __shfl_xor(v, 1); v += __shfl_xor(v, 2); v += __shfl_xor(v, 4);
        v += __shfl_xor(v, 8); v += __shfl_xor(v, 16); v += __shfl_xor(v, 32);
        sx[i] = v;
    }
    {
        float v = cc;
        v += __shfl_xor(v, 1); v += __shfl_xor(v, 2); v += __shfl_xor(v, 4);
        v += __shfl_xor(v, 8); v += __shfl_xor(v, 16); v += __shfl_xor(v, 32);
        cc = v;
    }
    if (lane == 0) {
        #pragma unroll
        for (int i = 0; i < 45; i++) red[wv][i] = M[i];
        #pragma unroll
        for (int i = 0; i < 9; i++) red[wv][45 + i] = sx[i];
        red[wv][54] = cc;
    }
    __syncthreads();
    if (t < 55) atomicAdd(&S[400 + t], red[0][t] + red[1][t] + red[2][t] + red[3][t]);
}

__global__ void k_finalize_mom(const float* __restrict__ Wpre,
                               const float* __restrict__ g, const float* __restrict__ b,
                               float* __restrict__ S) {
    int c = threadIdx.x;
    if (c < 64) {
        float w[9];
        #pragma unroll
        for (int j = 0; j < 9; j++) w[j] = Wpre[c * 9 + j];
        float cnt = fmaxf(S[454], 1.f);
        float s1 = 0.f;
        #pragma unroll
        for (int j = 0; j < 9; j++) s1 += w[j] * S[445 + j];
        float s2 = 0.f;
        int k = 0;
        #pragma unroll
        for (int a = 0; a < 9; a++)
            #pragma unroll
            for (int b2 = a; b2 < 9; b2++) {
                float mm = S[400 + k];
                s2 += (a == b2) ? w[a] * w[a] * mm : 2.f * w[a] * w[b2] * mm;
                k++;
            }
        float mean = s1 / cnt;
        float var = fmaxf(s2 / cnt - mean * mean, 0.f);
        float sc = g[c] * rsqrtf(var + EPS_);
        float sh = b[c] - mean * sc;
        S[512 + c] = sc;
        S[576 + c] = sh;
        if (c == 0) S[384] = S[454];
    }
}

// ---- shared helpers --------------------------------------------------------
__device__ __forceinline__ void mm_acc(float a[4][8], v4f av, v4f w0, v4f w1) {
    #pragma unroll
    for (int i = 0; i < 4; i++) {
        #pragma unroll
        for (int j = 0; j < 4; j++) {
            a[i][j] += av[i] * w0[j];
            a[i][4 + j] += av[i] * w1[j];
        }
    }
}

__device__ __forceinline__ void tzero(float a[4][8]) {
    #pragma unroll
    for (int i = 0; i < 4; i++)
        #pragma unroll
        for (int j = 0; j < 8; j++) a[i][j] = 0.f;
}

__device__ __forceinline__ void load_x(const float* xg, float* xTw, int lane) {
    for (int e = lane; e < 288; e += 64) {
        float v = xg[e];
        int p = e / 9, c = e - 9 * p;
        xTw[c * 36 + p] = v;
    }
}

__device__ __forceinline__ void stage1(const float* xTw, const float* WpT,
                                       int pg, int cg, float a1[4][8]) {
    tzero(a1);
    #pragma unroll
    for (int k = 0; k < 9; k++) {
        v4f av = ld4(xTw + k * 36 + 4 * pg);
        v4f w0 = ld4(WpT + k * 64 + 8 * cg);
        v4f w1 = ld4(WpT + k * 64 + 8 * cg + 4);
        mm_acc(a1, av, w0, w1);
    }
}

__device__ __forceinline__ void gemv64(const float* actw, const float* WT,
                                       int pg, int cg, float a[4][8]) {
    #pragma unroll 8
    for (int k = 0; k < 64; k++) {
        v4f av = ld4(actw + k * 32 + 4 * (pg ^ (k >> 3)));
        v4f w0 = ld4(WT + k * 64 + 8 * cg);
        v4f w1 = ld4(WT + k * 64 + 8 * cg + 4);
        mm_acc(a, av, w0, w1);
    }
}

__device__ __forceinline__ void bn_store_act(float* actw, const float a[4][8],
                                             const float* sc, const float* sh,
                                             const float m[4], int pg, int cg,
                                             float f[4][8]) {
    #pragma unroll
    for (int j = 0; j < 8; j++) {
        v4f v;
        #pragma unroll
        for (int i = 0; i < 4; i++) {
            float x = fmaxf(a[i][j] * sc[j] + sh[j], 0.f) * m[i];
            v[i] = x; f[i][j] = x;
        }
        st4(actw + (8 * cg + j) * 32 + 4 * (pg ^ cg), v);
    }
}

__device__ __forceinline__ void pool_reduce(const float f[4][8], float pmax[8]) {
    #pragma unroll
    for (int j = 0; j < 8; j++) {
        float v = fmaxf(fmaxf(f[0][j], f[1][j]), fmaxf(f[2][j], f[3][j]));
        v = fmaxf(v, __shfl_xor(v, 8));
        v = fmaxf(v, __shfl_xor(v, 16));
        v = fmaxf(v, __shfl_xor(v, 32));
        pmax[j] = v;
    }
}

__device__ __forceinline__ void qa_glob(const float pmax[8], const float* W1,
                                        float* pbufw, int pg, int cg, float qa[8]) {
    if (pg == 0)
        #pragma unroll
        for (int j = 0; j < 8; j++) pbufw[8 * cg + j] = pmax[j];
    __builtin_amdgcn_wave_barrier();
    #pragma unroll
    for (int j = 0; j < 8; j++) qa[j] = 0.f;
    #pragma unroll 4
    for (int kk = 0; kk < 16; kk++) {
        float p0 = pbufw[4 * kk], p1 = pbufw[4 * kk + 1];
        float p2 = pbufw[4 * kk + 2], p3 = pbufw[4 * kk + 3];
        #pragma unroll
        for (int j = 0; j < 8; j++) {
            v4f w = ld4(W1 + (8 * cg + j) * 128 + 64 + 4 * kk);
            qa[j] += w[0] * p0 + w[1] * p1 + w[2] * p2 + w[3] * p3;
        }
    }
}

__device__ __forceinline__ void stats_acc(const float a[4][8], const float m[4],
                                          float sp[8], float ssp[8]) {
    #pragma unroll
    for (int i = 0; i < 4; i++)
        #pragma unroll
        for (int j = 0; j < 8; j++) {
            float hv = a[i][j] * m[i];
            sp[j] += hv; ssp[j] += hv * a[i][j];
        }
}

__device__ __forceinline__ void stats_flush(float sp[8], float ssp[8],
                                            float (*red_s)[64], float (*red_ss)[64],
                                            float* S, int base, int t, int wv,
                                            int pg, int cg) {
    #pragma unroll
    for (int j = 0; j < 8; j++) {
        float v = sp[j];
        v += __shfl_xor(v, 8); v += __shfl_xor(v, 16); v += __shfl_xor(v, 32);
        sp[j] = v;
        float w = ssp[j];
        w += __shfl_xor(w, 8); w += __shfl_xor(w, 16); w += __shfl_xor(w, 32);
        ssp[j] = w;
    }
    if (pg == 0)
        #pragma unroll
        for (int j = 0; j < 8; j++) { red_s[wv][8 * cg + j] = sp[j]; red_ss[wv][8 * cg + j] = ssp[j]; }
    __syncthreads();
    if (t < 64) {
        atomicAdd(&S[base + t], red_s[0][t] + red_s[1][t] + red_s[2][t] + red_s[3][t]);
        atomicAdd(&S[base + 64 + t], red_ss[0][t] + red_ss[1][t] + red_ss[2][t] + red_ss[3][t]);
    }
}

// ---- pass 2 (big ws): MFMA stage2, W1-frags in LDS, SW-pipelined (R2-proven)
// Stage2 MFMA: A=W1 (K=128), B=[feat;pooled]. Stage1 VALU in B-layout.
// Layouts (HW-validated): A[m=lane&15][k=quad*8+j], B[k=quad*8+j][n=lane&15],
// C: col(n)=lane&15, row(m)=mt*16+quad*4+r.
__global__ __launch_bounds__(256) void k_stats2_mfma(const float* __restrict__ poly,
                                                     const int* __restrict__ mask,
                                                     const float* __restrict__ Wpre,
                                                     const float* __restrict__ gpre,
                                                     const float* __restrict__ bpre,
                                                     const float* __restrict__ W1,
                                                     float* __restrict__ S,
                                                     u16* __restrict__ H16) {
    __shared__ __align__(16) float WpT[576];
    __shared__ __align__(16) float xT[4][324];
    __shared__ float scsh[128];
    __shared__ float red_s[4][64], red_ss[4][64];
    __shared__ __align__(16) uint4 awl[16 * 64];   // 16KB: W1 A-frags, lane-ordered
    const int t = threadIdx.x, wv = t >> 6, lane = t & 63;
    const int n = lane & 15, quad = lane >> 4;
    for (int i = t; i < 576; i += 256) { int c = i >> 6, ch = i & 63; WpT[i] = Wpre[ch * 9 + c]; }

    // inline BN1 finalize from moments (cold preamble)
    if (t < 64) {
        float w[9];
        #pragma unroll
        for (int j = 0; j < 9; j++) w[j] = Wpre[t * 9 + j];
        float cnt = fmaxf(S[454], 1.f);
        float s1 = 0.f;
        #pragma unroll
        for (int j = 0; j < 9; j++) s1 += w[j] * S[445 + j];
        float s2 = 0.f;
        int k = 0;
        #pragma unroll
        for (int a = 0; a < 9; a++)
            #pragma unroll
            for (int b2 = a; b2 < 9; b2++) {
                float mm = S[400 + k];
                s2 += (a == b2) ? w[a] * w[a] * mm : 2.f * w[a] * w[b2] * mm;
                k++;
            }
        float mean = s1 / cnt;
        float var = fmaxf(s2 / cnt - mean * mean, 0.f);
        float sc = gpre[t] * rsqrtf(var + EPS_);
        scsh[t] = sc;
        scsh[64 + t] = bpre[t] - mean * sc;
    }

    // build shared A-fragment table: wave wv packs mt=wv (frag depends only on lane)
    #pragma unroll
    for (int ss = 0; ss < 4; ss++) {
        const float* wr = W1 + (size_t)(wv * 16 + n) * 128 + ss * 32 + quad * 8;
        union { uint4 q; u32 w[4]; } uu;
        #pragma unroll
        for (int d = 0; d < 4; d++) uu.w[d] = pack2bf(wr[2 * d], wr[2 * d + 1]);
        awl[(wv * 4 + ss) * 64 + lane] = uu.q;
    }
    __syncthreads();
    float sck[16], shk[16];
    #pragma unroll
    for (int s = 0; s < 2; s++)
        #pragma unroll
        for (int j = 0; j < 8; j++) {
            int c = s * 32 + quad * 8 + j;
            sck[s * 8 + j] = scsh[c];
            shk[s * 8 + j] = scsh[64 + c];
        }

    float sp16[16], ssp16[16];
    #pragma unroll
    for (int e = 0; e < 16; e++) { sp16[e] = 0.f; ssp16[e] = 0.f; }

    // loop-invariant transpose-scatter addresses (e/9 hoisted out of the loop)
    int ax0, ax1, ax2, ax3, ax4;
    {
        int e = lane;        int p = e / 9; ax0 = (e - 9 * p) * 36 + p;
        e = lane + 64;       p = e / 9;     ax1 = (e - 9 * p) * 36 + p;
        e = lane + 128;      p = e / 9;     ax2 = (e - 9 * p) * 36 + p;
        e = lane + 192;      p = e / 9;     ax3 = (e - 9 * p) * 36 + p;
        e = lane + 256;      p = e / 9;     ax4 = (e - 9 * p) * 36 + p;
    }

    const sv8* awp = (const sv8*)awl;
    const int wgid = blockIdx.x * 4 + wv;
    // prologue prefetch: polyline wgid
    float xr0, xr1, xr2, xr3, xr4, mvr;
    {
        const float* xg = poly + (size_t)wgid * 288;
        xr0 = xg[lane]; xr1 = xg[lane + 64]; xr2 = xg[lane + 128]; xr3 = xg[lane + 192];
        xr4 = (lane < 32) ? xg[256 + lane] : 0.f;
        mvr = (lane < 32 && mask[wgid * 32 + lane] != 0) ? 1.f : 0.f;
    }

    for (int it = 0; it < NIT2; it++) {
        const int bn = wgid + it * TOTW2;
        const float mv = mvr;
        // scatter prefetched x into per-wave LDS tile
        xT[wv][ax0] = xr0; xT[wv][ax1] = xr1; xT[wv][ax2] = xr2; xT[wv][ax3] = xr3;
        if (lane < 32) xT[wv][ax4] = xr4;
        __builtin_amdgcn_wave_barrier();
        // issue next polyline's loads; latency hides under this iteration's compute
        if (it < NIT2 - 1) {
            const int bnn = bn + TOTW2;
            const float* xg = poly + (size_t)bnn * 288;
            xr0 = xg[lane]; xr1 = xg[lane + 64]; xr2 = xg[lane + 128]; xr3 = xg[lane + 192];
            if (lane < 32) {
                xr4 = xg[256 + lane];
                mvr = (mask[bnn * 32 + lane] != 0) ? 1.f : 0.f;
            }
        }
        // stage1 (VALU) for points {n, 16+n}, channels {s*32+quad*8+j}
        float f0[16], f1[16];
        #pragma unroll
        for (int e = 0; e < 16; e++) { f0[e] = 0.f; f1[e] = 0.f; }
        #pragma unroll
        for (int k = 0; k < 9; k++) {
            float x0 = xT[wv][k * 36 + n];
            float x1 = xT[wv][k * 36 + 16 + n];
            v4f wA0 = ld4(WpT + k * 64 + quad * 8);
            v4f wA1 = ld4(WpT + k * 64 + quad * 8 + 4);
            v4f wB0 = ld4(WpT + k * 64 + 32 + quad * 8);
            v4f wB1 = ld4(WpT + k * 64 + 32 + quad * 8 + 4);
            #pragma unroll
            for (int j = 0; j < 4; j++) {
                f0[j] += x0 * wA0[j];  f0[4 + j] += x0 * wA1[j];
                f0[8 + j] += x0 * wB0[j]; f0[12 + j] += x0 * wB1[j];
                f1[j] += x1 * wA0[j];  f1[4 + j] += x1 * wA1[j];
                f1[8 + j] += x1 * wB0[j]; f1[12 + j] += x1 * wB1[j];
            }
        }
        float mp0 = __shfl(mv, n), mp1 = __shfl(mv, 16 + n);
        #pragma unroll
        for (int e = 0; e < 16; e++) {
            f0[e] = fmaxf(f0[e] * sck[e] + shk[e], 0.f) * mp0;
            f1[e] = fmaxf(f1[e] * sck[e] + shk[e], 0.f) * mp1;
        }
        float pm[16];
        #pragma unroll
        for (int e = 0; e < 16; e++) {
            float v = fmaxf(f0[e], f1[e]);
            v = fmaxf(v, __shfl_xor(v, 1));
            v = fmaxf(v, __shfl_xor(v, 2));
            v = fmaxf(v, __shfl_xor(v, 4));
            v = fmaxf(v, __shfl_xor(v, 8));
            pm[e] = v;
        }
        sv8 bg0[2], bg1[2], bp[2];
        #pragma unroll
        for (int s = 0; s < 2; s++) {
            union { sv8 v; u32 w[4]; } a, b, c;
            #pragma unroll
            for (int d = 0; d < 4; d++) {
                a.w[d] = pack2bf(f0[s * 8 + 2 * d], f0[s * 8 + 2 * d + 1]);
                b.w[d] = pack2bf(f1[s * 8 + 2 * d], f1[s * 8 + 2 * d + 1]);
                c.w[d] = pack2bf(pm[s * 8 + 2 * d], pm[s * 8 + 2 * d + 1]);
            }
            bg0[s] = a.v; bg1[s] = b.v; bp[s] = c.v;
        }
        // per-mt MFMA: A-frags from LDS (short-lived), acc dies after stats+store
        u16* Hw = H16 + (size_t)bn * 2048;
        #pragma unroll
        for (int mt = 0; mt < 4; mt++) {
            sv8 a0 = awp[(mt * 4 + 0) * 64 + lane];
            sv8 a1 = awp[(mt * 4 + 1) * 64 + lane];
            sv8 a2 = awp[(mt * 4 + 2) * 64 + lane];
            sv8 a3 = awp[(mt * 4 + 3) * 64 + lane];
            fv4 c0 = {0.f, 0.f, 0.f, 0.f}, c1 = {0.f, 0.f, 0.f, 0.f};
            c0 = __builtin_amdgcn_mfma_f32_16x16x32_bf16(a0, bg0[0], c0, 0, 0, 0);
            c0 = __builtin_amdgcn_mfma_f32_16x16x32_bf16(a1, bg0[1], c0, 0, 0, 0);
            c0 = __builtin_amdgcn_mfma_f32_16x16x32_bf16(a2, bp[0], c0, 0, 0, 0);
            c0 = __builtin_amdgcn_mfma_f32_16x16x32_bf16(a3, bp[1], c0, 0, 0, 0);
            c1 = __builtin_amdgcn_mfma_f32_16x16x32_bf16(a0, bg1[0], c1, 0, 0, 0);
            c1 = __builtin_amdgcn_mfma_f32_16x16x32_bf16(a1, bg1[1], c1, 0, 0, 0);
            c1 = __builtin_amdgcn_mfma_f32_16x16x32_bf16(a2, bp[0], c1, 0, 0, 0);
            c1 = __builtin_amdgcn_mfma_f32_16x16x32_bf16(a3, bp[1], c1, 0, 0, 0);
            #pragma unroll
            for (int r = 0; r < 4; r++) {
                sp16[mt * 4 + r] += c0[r] * mp0 + c1[r] * mp1;
                ssp16[mt * 4 + r] += c0[r] * c0[r] * mp0 + c1[r] * c1[r] * mp1;
            }
            uint2 pk0, pk1;
            pk0.x = pack2bf(c0[0], c0[1]); pk0.y = pack2bf(c0[2], c0[3]);
            pk1.x = pack2bf(c1[0], c1[1]); pk1.y = pack2bf(c1[2], c1[3]);
            *(uint2*)(Hw + mt * 512 + lane * 4) = pk0;
            *(uint2*)(Hw + mt * 512 + 256 + lane * 4) = pk1;
        }
        __builtin_amdgcn_wave_barrier();
    }
    #pragma unroll
    for (int e = 0; e < 16; e++) {
        float v = sp16[e];
        v += __shfl_xor(v, 1); v += __shfl_xor(v, 2); v += __shfl_xor(v, 4); v += __shfl_xor(v, 8);
        sp16[e] = v;
        float w = ssp16[e];
        w += __shfl_xor(w, 1); w += __shfl_xor(w, 2); w += __shfl_xor(w, 4); w += __shfl_xor(w, 8);
        ssp16[e] = w;
    }
    if (n == 0) {
        #pragma unroll
        for (int mt = 0; mt < 4; mt++)
            #pragma unroll
            for (int r = 0; r < 4; r++) {
                red_s[wv][mt * 16 + quad * 4 + r] = sp16[mt * 4 + r];
                red_ss[wv][mt * 16 + quad * 4 + r] = ssp16[mt * 4 + r];
            }
    }
    __syncthreads();
    if (t < 64) {
        atomicAdd(&S[128 + t], red_s[0][t] + red_s[1][t] + red_s[2][t] + red_s[3][t]);
        atomicAdd(&S[128 + 64 + t], red_ss[0][t] + red_ss[1][t] + red_ss[2][t] + red_ss[3][t]);
    }
}

// ---- pass 3 (big ws): MFMA-native H16 in/out, W2-frags in LDS --------------
__global__ __launch_bounds__(256) void k_stats3_mfma(const int* __restrict__ mask,
                                                     const float* __restrict__ g1,
                                                     const float* __restrict__ b1,
                                                     const float* __restrict__ W2,
                                                     float* __restrict__ S,
                                                     u16* __restrict__ H16) {
    __shared__ float scsh[128];
    __shared__ float red_s[4][64], red_ss[4][64];
    __shared__ __align__(16) uint4 awl[8 * 64];   // 8KB: W2 A-frags, lane-ordered
    const int t = threadIdx.x, wv = t >> 6, lane = t & 63;
    const int n = lane & 15, quad = lane >> 4;

    if (t < 64) {
        float cnt = fmaxf(S[454], 1.f);
        float mean = S[128 + t] / cnt;
        float var = fmaxf(S[192 + t] / cnt - mean * mean, 0.f);
        float sc = g1[t] * rsqrtf(var + EPS_);
        scsh[t] = sc;
        scsh[64 + t] = b1[t] - mean * sc;
    }

    #pragma unroll
    for (int s = 0; s < 2; s++) {
        const float* wr = W2 + (wv * 16 + n) * 64 + s * 32 + quad * 8;
        union { uint4 q; u32 w[4]; } uu;
        #pragma unroll
        for (int d = 0; d < 4; d++) uu.w[d] = pack2bf(wr[2 * d], wr[2 * d + 1]);
        awl[(wv * 2 + s) * 64 + lane] = uu.q;
    }
    __syncthreads();
    float sck[16], shk[16];
    #pragma unroll
    for (int s = 0; s < 2; s++)
        #pragma unroll
        for (int j = 0; j < 8; j++) {
            int k = s * 32 + quad * 8 + j;
            sck[s * 8 + j] = scsh[k];
            shk[s * 8 + j] = scsh[64 + k];
        }

    float sp16[16], ssp16[16];
    #pragma unroll
    for (int e = 0; e < 16; e++) { sp16[e] = 0.f; ssp16[e] = 0.f; }

    const sv8* awp = (const sv8*)awl;
    const int wgid = blockIdx.x * 4 + wv;
    // reader offset for B-fragment gather: ch = s*32+quad*8+j ->
    //   mt' = s*2+(quad>>1), quad'_base = (quad&1)*2 (+ j>>2), r = j&3
    const int hoff = (quad >> 1) * 512 + (quad & 1) * 128 + n * 4;
    uint2 hr[2][2][2];   // [nt][s][half]
    float mvr;
    {
        const u16* Hb = H16 + (size_t)wgid * 2048;
        #pragma unroll
        for (int nt = 0; nt < 2; nt++)
            #pragma unroll
            for (int s = 0; s < 2; s++)
                #pragma unroll
                for (int h = 0; h < 2; h++)
                    hr[nt][s][h] = *(const uint2*)(Hb + hoff + s * 1024 + nt * 256 + h * 64);
        mvr = (lane < 32 && mask[wgid * 32 + lane] != 0) ? 1.f : 0.f;
    }

    for (int it = 0; it < NIT2; it++) {
        const int bn = wgid + it * TOTW2;
        const float mv = mvr;
        float mpn[2] = {__shfl(mv, n), __shfl(mv, 16 + n)};
        sv8 bg[2][2];
        #pragma unroll
        for (int nt = 0; nt < 2; nt++)
            #pragma unroll
            for (int s = 0; s < 2; s++) {
                u32 ws[4] = {hr[nt][s][0].x, hr[nt][s][0].y, hr[nt][s][1].x, hr[nt][s][1].y};
                union { sv8 v; u32 w[4]; } uu;
                #pragma unroll
                for (int d = 0; d < 4; d++) {
                    union { u32 u; float f; } lo, hi;
                    lo.u = ws[d] << 16; hi.u = ws[d] & 0xFFFF0000u;
                    float g0 = fmaxf(lo.f * sck[s * 8 + 2 * d] + shk[s * 8 + 2 * d], 0.f) * mpn[nt];
                    float g1v = fmaxf(hi.f * sck[s * 8 + 2 * d + 1] + shk[s * 8 + 2 * d + 1], 0.f) * mpn[nt];
                    uu.w[d] = pack2bf(g0, g1v);
                }
                bg[nt][s] = uu.v;
            }
        // prefetch next polyline's h1 fragments (hr fully consumed above)
        if (it < NIT2 - 1) {
            const int bnn = bn + TOTW2;
            const u16* Hb = H16 + (size_t)bnn * 2048;
            #pragma unroll
            for (int nt = 0; nt < 2; nt++)
                #pragma unroll
                for (int s = 0; s < 2; s++)
                    #pragma unroll
                    for (int h = 0; h < 2; h++)
                        hr[nt][s][h] = *(const uint2*)(Hb + hoff + s * 1024 + nt * 256 + h * 64);
            if (lane < 32) mvr = (mask[bnn * 32 + lane] != 0) ? 1.f : 0.f;
        }
        u16* Hw = H16 + (size_t)bn * 2048;
        #pragma unroll
        for (int nt = 0; nt < 2; nt++) {
            float mp = mpn[nt];
            #pragma unroll
            for (int mt = 0; mt < 4; mt++) {
                sv8 a0 = awp[(mt * 2 + 0) * 64 + lane];
                sv8 a1 = awp[(mt * 2 + 1) * 64 + lane];
                fv4 c = {0.f, 0.f, 0.f, 0.f};
                c = __builtin_amdgcn_mfma_f32_16x16x32_bf16(a0, bg[nt][0], c, 0, 0, 0);
                c = __builtin_amdgcn_mfma_f32_16x16x32_bf16(a1, bg[nt][1], c, 0, 0, 0);
                #pragma unroll
                for (int r = 0; r < 4; r++) {
                    sp16[mt * 4 + r] += c[r] * mp;
                    ssp16[mt * 4 + r] += c[r] * c[r] * mp;
                }
                uint2 pk;
                pk.x = pack2bf(c[0], c[1]);
                pk.y = pack2bf(c[2], c[3]);
                *(uint2*)(Hw + mt * 512 + nt * 256 + lane * 4) = pk;
            }
        }
    }
    #pragma unroll
    for (int e = 0; e < 16; e++) {
        float v = sp16[e];
        v += __shfl_xor(v, 1); v += __shfl_xor(v, 2); v += __shfl_xor(v, 4); v += __shfl_xor(v, 8);
        sp16[e] = v;
        float w = ssp16[e];
        w += __shfl_xor(w, 1); w += __shfl_xor(w, 2); w += __shfl_xor(w, 4); w += __shfl_xor(w, 8);
        ssp16[e] = w;
    }
    if (n == 0) {
        #pragma unroll
        for (int mt = 0; mt < 4; mt++)
            #pragma unroll
            for (int r = 0; r < 4; r++) {
                red_s[wv][mt * 16 + quad * 4 + r] = sp16[mt * 4 + r];
                red_ss[wv][mt * 16 + quad * 4 + r] = ssp16[mt * 4 + r];
            }
    }
    __syncthreads();
    if (t < 64) {
        atomicAdd(&S[256 + t], red_s[0][t] + red_s[1][t] + red_s[2][t] + red_s[3][t]);
        atomicAdd(&S[256 + 64 + t], red_ss[0][t] + red_ss[1][t] + red_ss[2][t] + red_ss[3][t]);
    }
}

// ---- pass 4 (big ws): MFMA-native H16 read, Wo1T+Wo2T in LDS (R0-proven) ---
__global__ __launch_bounds__(256) void k_out_load(const int* __restrict__ mask,
                                                  const float* __restrict__ g2,
                                                  const float* __restrict__ b2,
                                                  const float* __restrict__ Wo1,
                                                  const float* __restrict__ bo1,
                                                  const float* __restrict__ Wo2,
                                                  const float* __restrict__ bo2,
                                                  const float* __restrict__ S,
                                                  const u16* __restrict__ H16,
                                                  float* __restrict__ out) {
    __shared__ __align__(16) float Wo1T[4096];
    __shared__ __align__(16) float Wo2T[8192];
    __shared__ float pbuf[4][64];
    __shared__ float scsh[128];
    const int t = threadIdx.x, wv = t >> 6, lane = t & 63;
    const int n = lane & 15, quad = lane >> 4;
    if (t < 64) {
        float cnt = fmaxf(S[454], 1.f);
        float mean = S[256 + t] / cnt;
        float var = fmaxf(S[320 + t] / cnt - mean * mean, 0.f);
        float sc = g2[t] * rsqrtf(var + EPS_);
        scsh[t] = sc;
        scsh[64 + t] = b2[t] - mean * sc;
    }
    for (int i = t; i < 4096; i += 256) { int k = i >> 6, ch = i & 63; Wo1T[i] = Wo1[ch * 64 + k]; }
    for (int i = t; i < 8192; i += 256) { int k = i >> 7, o = i & 127; Wo2T[i] = Wo2[o * 64 + k]; }
    __syncthreads();
    float sc3[16], sh3[16];
    #pragma unroll
    for (int mt = 0; mt < 4; mt++)
        #pragma unroll
        for (int r = 0; r < 4; r++) {
            sc3[mt * 4 + r] = scsh[mt * 16 + quad * 4 + r];
            sh3[mt * 4 + r] = scsh[64 + mt * 16 + quad * 4 + r];
        }
    float bo1v = bo1[lane], bo2a = bo2[lane], bo2b = bo2[64 + lane];
    const int wgid = blockIdx.x * 4 + wv;
    uint2 hr[4][2];   // [mt][nt]
    float mvr;
    {
        const u16* Hb = H16 + (size_t)wgid * 2048;
        #pragma unroll
        for (int mt = 0; mt < 4; mt++)
            #pragma unroll
            for (int nt = 0; nt < 2; nt++)
                hr[mt][nt] = *(const uint2*)(Hb + mt * 512 + nt * 256 + lane * 4);
        mvr = (lane < 32 && mask[wgid * 32 + lane] != 0) ? 1.f : 0.f;
    }
    for (int it = 0; it < NITO; it++) {
        const int bn = wgid + it * TOTWO;
        const float mv = mvr;
        float mpn[2] = {__shfl(mv, n), __shfl(mv, 16 + n)};
        float vf = __ballot(mv > 0.5f) ? 1.f : 0.f;
        float pm[16];
        #pragma unroll
        for (int mt = 0; mt < 4; mt++)
            #pragma unroll
            for (int nt = 0; nt < 2; nt++) {
                u32 wx = hr[mt][nt].x, wy = hr[mt][nt].y;
                float v0 = bf2f((u16)(wx & 0xFFFFu)), v1 = bf2f((u16)(wx >> 16));
                float v2 = bf2f((u16)(wy & 0xFFFFu)), v3 = bf2f((u16)(wy >> 16));
                float mp = mpn[nt];
                float e0 = fmaxf(v0 * sc3[mt * 4 + 0] + sh3[mt * 4 + 0], 0.f) * mp;
                float e1 = fmaxf(v1 * sc3[mt * 4 + 1] + sh3[mt * 4 + 1], 0.f) * mp;
                float e2 = fmaxf(v2 * sc3[mt * 4 + 2] + sh3[mt * 4 + 2], 0.f) * mp;
                float e3 = fmaxf(v3 * sc3[mt * 4 + 3] + sh3[mt * 4 + 3], 0.f) * mp;
                if (nt == 0) {
                    pm[mt * 4 + 0] = e0; pm[mt * 4 + 1] = e1;
                    pm[mt * 4 + 2] = e2; pm[mt * 4 + 3] = e3;
                } else {
                    pm[mt * 4 + 0] = fmaxf(pm[mt * 4 + 0], e0);
                    pm[mt * 4 + 1] = fmaxf(pm[mt * 4 + 1], e1);
                    pm[mt * 4 + 2] = fmaxf(pm[mt * 4 + 2], e2);
                    pm[mt * 4 + 3] = fmaxf(pm[mt * 4 + 3], e3);
                }
            }
        if (it < NITO - 1) {
            const int bnn = bn + TOTWO;
            const u16* Hb = H16 + (size_t)bnn * 2048;
            #pragma unroll
            for (int mt = 0; mt < 4; mt++)
                #pragma unroll
                for (int nt = 0; nt < 2; nt++)
                    hr[mt][nt] = *(const uint2*)(Hb + mt * 512 + nt * 256 + lane * 4);
            if (lane < 32) mvr = (mask[bnn * 32 + lane] != 0) ? 1.f : 0.f;
        }
        #pragma unroll
        for (int e = 0; e < 16; e++) {
            float v = pm[e];
            v = fmaxf(v, __shfl_xor(v, 1));
            v = fmaxf(v, __shfl_xor(v, 2));
            v = fmaxf(v, __shfl_xor(v, 4));
            v = fmaxf(v, __shfl_xor(v, 8));
            pm[e] = v;
        }
        if (n == 0) {
            #pragma unroll
            for (int mt = 0; mt < 4; mt++)
                #pragma unroll
                for (int r = 0; r < 4; r++)
                    pbuf[wv][mt * 16 + quad * 4 + r] = pm[mt * 4 + r];
        }
        __builtin_amdgcn_wave_barrier();
        float y1 = bo1v;
        #pragma unroll 8
        for (int k = 0; k < 64; k++) y1 += Wo1T[k * 64 + lane] * pbuf[wv][k];
        y1 = fmaxf(y1, 0.f);
        pbuf[wv][lane] = y1;
        __builtin_amdgcn_wave_barrier();
        float o0 = bo2a, o1 = bo2b;
        #pragma unroll 8
        for (int k = 0; k < 64; k++) {
            float yv = pbuf[wv][k];
            o0 += Wo2T[k * 128 + lane] * yv;
            o1 += Wo2T[k * 128 + 64 + lane] * yv;
        }
        out[(size_t)bn * 128 + lane] = o0 * vf;
        out[(size_t)bn * 128 + 64 + lane] = o1 * vf;
        __builtin_amdgcn_wave_barrier();
    }
}

// ---- fallback (small ws): recompute path, untouched ------------------------
__device__ __forceinline__ void qa_lds_fb(const float pmax[8], const float* W1pT,
                                          int cg, float qa[8]) {
    #pragma unroll
    for (int j = 0; j < 8; j++) qa[j] = 0.f;
    #pragma unroll
    for (int k = 0; k < 64; k++) {
        float pv = __shfl(pmax[k & 7], k >> 3);
        v4f w0 = ld4(W1pT + k * 64 + 8 * cg);
        v4f w1 = ld4(W1pT + k * 64 + 8 * cg + 4);
        #pragma unroll
        for (int j = 0; j < 4; j++) { qa[j] += pv * w0[j]; qa[4 + j] += pv * w1[j]; }
    }
}

__global__ __launch_bounds__(256) void k_stats2_fb(const float* __restrict__ poly,
                                                   const int* __restrict__ mask,
                                                   const float* __restrict__ Wpre,
                                                   const float* __restrict__ W1,
                                                   float* __restrict__ S) {
    __shared__ __align__(16) float WpT[576];
    __shared__ __align__(16) float W1aT[4096];
    __shared__ __align__(16) float W1pT[4096];
    __shared__ __align__(16) float act[4][2048];
    __shared__ __align__(16) float xT[4][324];
    __shared__ float red_s[4][64], red_ss[4][64];
    const int t = threadIdx.x, wv = t >> 6, lane = t & 63;
    const int pg = lane >> 3, cg = lane & 7;
    for (int i = t; i < 576; i += 256) { int c = i >> 6, ch = i & 63; WpT[i] = Wpre[ch * 9 + c]; }
    for (int i = t; i < 4096; i += 256) {
        int k = i >> 6, ch = i & 63;
        W1aT[i] = W1[ch * 128 + k];
        W1pT[i] = W1[ch * 128 + 64 + k];
    }
    __syncthreads();
    float sc1[8], sh1[8];
    #pragma unroll
    for (int j = 0; j < 8; j++) { sc1[j] = S[512 + 8 * cg + j]; sh1[j] = S[576 + 8 * cg + j]; }
    float sp[8] = {0}, ssp[8] = {0};
    const int wgid = blockIdx.x * 4 + wv;
    for (int bn = wgid; bn < BN_TOT; bn += TOTW) {
        float mv = (lane < 32 && mask[bn * 32 + lane] != 0) ? 1.f : 0.f;
        float m[4];
        #pragma unroll
        for (int i = 0; i < 4; i++) m[i] = __shfl(mv, 4 * pg + i);
        load_x(poly + (size_t)bn * 288, xT[wv], lane);
        __builtin_amdgcn_wave_barrier();
        float a1[4][8], f[4][8];
        stage1(xT[wv], WpT, pg, cg, a1);
        bn_store_act(act[wv], a1, sc1, sh1, m, pg, cg, f);
        float pmax[8], qa[8];
        pool_reduce(f, pmax);
        qa_lds_fb(pmax, W1pT, cg, qa);
        __builtin_amdgcn_wave_barrier();
        float a2[4][8];
        #pragma unroll
        for (int i = 0; i < 4; i++)
            #pragma unroll
            for (int j = 0; j < 8; j++) a2[i][j] = qa[j];
        gemv64(act[wv], W1aT, pg, cg, a2);
        stats_acc(a2, m, sp, ssp);
        __builtin_amdgcn_wave_barrier();
    }
    stats_flush(sp, ssp, red_s, red_ss, S, 128, t, wv, pg, cg);
}

template<bool DO_OUT>
__global__ __launch_bounds__(256) void k_rec34(const float* __restrict__ poly,
                                               const int* __restrict__ mask,
                                               const float* __restrict__ Wpre,
                                               const float* __restrict__ W1,
                                               const float* __restrict__ W2,
                                               const float* __restrict__ Wo1,
                                               const float* __restrict__ bo1,
                                               const float* __restrict__ Wo2,
                                               const float* __restrict__ bo2,
                                               float* __restrict__ S,
                                               float* __restrict__ out) {
    __shared__ __align__(16) float WpT[576];
    __shared__ __align__(16) float W1aT[4096];
    __shared__ __align__(16) float W2T[4096];
    __shared__ __align__(16) float act[4][2048];
    __shared__ __align__(16) float xT[4][324];
    __shared__ float pbuf[4][64];
    __shared__ float red_s[4][64], red_ss[4][64];
    const int t = threadIdx.x, wv = t >> 6, lane = t & 63;
    const int pg = lane >> 3, cg = lane & 7;
    for (int i = t; i < 576; i += 256) { int c = i >> 6, ch = i & 63; WpT[i] = Wpre[ch * 9 + c]; }
    for (int i = t; i < 4096; i += 256) {
        int k = i >> 6, ch = i & 63;
        W1aT[i] = W1[ch * 128 + k];
        W2T[i] = W2[ch * 64 + k];
    }
    __syncthreads();
    float sc1[8], sh1[8], sc2[8], sh2[8], sc3[8], sh3[8];
    #pragma unroll
    for (int j = 0; j < 8; j++) {
        sc1[j] = S[512 + 8 * cg + j]; sh1[j] = S[576 + 8 * cg + j];
        sc2[j] = S[640 + 8 * cg + j]; sh2[j] = S[704 + 8 * cg + j];
    }
    if constexpr (DO_OUT)
        #pragma unroll
        for (int j = 0; j < 8; j++) { sc3[j] = S[768 + 8 * cg + j]; sh3[j] = S[832 + 8 * cg + j]; }
    float bo1v = 0.f, bo2a = 0.f, bo2b = 0.f;
    if constexpr (DO_OUT) { bo1v = bo1[lane]; bo2a = bo2[lane]; bo2b = bo2[64 + lane]; }
    float sp[8] = {0}, ssp[8] = {0};
    const int wgid = blockIdx.x * 4 + wv;
    for (int bn = wgid; bn < BN_TOT; bn += TOTW) {
        float mv = (lane < 32 && mask[bn * 32 + lane] != 0) ? 1.f : 0.f;
        float m[4];
        #pragma unroll
        for (int i = 0; i < 4; i++) m[i] = __shfl(mv, 4 * pg + i);
        load_x(poly + (size_t)bn * 288, xT[wv], lane);
        __builtin_amdgcn_wave_barrier();
        float a1[4][8], f[4][8];
        stage1(xT[wv], WpT, pg, cg, a1);
        bn_store_act(act[wv], a1, sc1, sh1, m, pg, cg, f);
        float pmax[8], qa[8];
        pool_reduce(f, pmax);
        qa_glob(pmax, W1, pbuf[wv], pg, cg, qa);
        __builtin_amdgcn_wave_barrier();
        float a2[4][8];
        #pragma unroll
        for (int i = 0; i < 4; i++)
            #pragma unroll
            for (int j = 0; j < 8; j++) a2[i][j] = qa[j];
        gemv64(act[wv], W1aT, pg, cg, a2);
        __builtin_amdgcn_wave_barrier();
        bn_store_act(act[wv], a2, sc2, sh2, m, pg, cg, f);
        __builtin_amdgcn_wave_barrier();
        float a3[4][8];
        tzero(a3);
        gemv64(act[wv], W2T, pg, cg, a3);
        if constexpr (!DO_OUT) {
            stats_acc(a3, m, sp, ssp);
        } else {
            float px[8];
            #pragma unroll
            for (int j = 0; j < 8; j++) {
                float v = 0.f;
                #pragma unroll
                for (int i = 0; i < 4; i++)
                    v = fmaxf(v, fmaxf(a3[i][j] * sc3[j] + sh3[j], 0.f) * m[i]);
                px[j] = v;
            }
            #pragma unroll
            for (int j = 0; j < 8; j++) {
                float v = px[j];
                v = fmaxf(v, __shfl_xor(v, 8));
                v = fmaxf(v, __shfl_xor(v, 16));
                v = fmaxf(v, __shfl_xor(v, 32));
                px[j] = v;
            }
            if (pg == 0)
                #pragma unroll
                for (int j = 0; j < 8; j++) pbuf[wv][8 * cg + j] = px[j];
            __builtin_amdgcn_wave_barrier();
            float y1 = bo1v;
            #pragma unroll 4
            for (int kk = 0; kk < 16; kk++) {
                v4f w = ld4(Wo1 + lane * 64 + 4 * kk);
                y1 += w[0] * pbuf[wv][4 * kk] + w[1] * pbuf[wv][4 * kk + 1]
                    + w[2] * pbuf[wv][4 * kk + 2] + w[3] * pbuf[wv][4 * kk + 3];
            }
            y1 = fmaxf(y1, 0.f);
            pbuf[wv][lane] = y1;
            __builtin_amdgcn_wave_barrier();
            float o0 = bo2a, o1 = bo2b;
            #pragma unroll 4
            for (int kk = 0; kk < 16; kk++) {
                v4f w0 = ld4(Wo2 + lane * 64 + 4 * kk);
                v4f w1 = ld4(Wo2 + (64 + lane) * 64 + 4 * kk);
                float p0 = pbuf[wv][4 * kk], p1 = pbuf[wv][4 * kk + 1];
                float p2 = pbuf[wv][4 * kk + 2], p3 = pbuf[wv][4 * kk + 3];
                o0 += w0[0] * p0 + w0[1] * p1 + w0[2] * p2 + w0[3] * p3;
                o1 += w1[0] * p0 + w1[1] * p1 + w1[2] * p2 + w1[3] * p3;
            }
            float vf = __ballot(mv > 0.5f) ? 1.f : 0.f;
            out[(size_t)bn * 128 + lane] = o0 * vf;
            out[(size_t)bn * 128 + 64 + lane] = o1 * vf;
        }
        __builtin_amdgcn_wave_barrier();
    }
    if constexpr (!DO_OUT)
        stats_flush(sp, ssp, red_s, red_ss, S, 256, t, wv, pg, cg);
}

extern "C" void kernel_launch(void* const* d_in, const int* in_sizes, int n_in,
                              void* d_out, int out_size, void* d_ws, size_t ws_size,
                              hipStream_t stream) {
    const float* poly = (const float*)d_in[0];
    const int*   mask = (const int*)d_in[1];
    const float* Wpre = (const float*)d_in[2];
    const float* gpre = (const float*)d_in[3];
    const float* bpre = (const float*)d_in[4];
    const float* W1   = (const float*)d_in[5];
    const float* g1   = (const float*)d_in[6];
    const float* b1   = (const float*)d_in[7];
    const float* W2   = (const float*)d_in[8];
    const float* g2   = (const float*)d_in[9];
    const float* b2   = (const float*)d_in[10];
    const float* Wo1  = (const float*)d_in[11];
    const float* bo1  = (const float*)d_in[12];
    const float* Wo2  = (const float*)d_in[13];
    const float* bo2  = (const float*)d_in[14];

    float* S = (float*)d_ws;
    u16* H16 = (u16*)((char*)d_ws + 8192);
    float* out = (float*)d_out;

    const size_t needWS = 8192 + (size_t)BN_TOT * 2048 * sizeof(u16);  // ~100.7 MB

    hipMemsetAsync(S, 0, 512 * sizeof(float), stream);
    k_mom<<<NBLK, 256, 0, stream>>>(poly, mask, S);
    if (ws_size >= needWS) {
        k_stats2_mfma<<<NB2, 256, 0, stream>>>(poly, mask, Wpre, gpre, bpre, W1, S, H16);
        k_stats3_mfma<<<NB2, 256, 0, stream>>>(mask, g1, b1, W2, S, H16);
        k_out_load<<<NBO, 256, 0, stream>>>(mask, g2, b2, Wo1, bo1, Wo2, bo2, S, H16, out);
    } else {
        k_finalize_mom<<<1, 64, 0, stream>>>(Wpre, gpre, bpre, S);
        k_stats2_fb<<<NBLK, 256, 0, stream>>>(poly, mask, Wpre, W1, S);
        k_finalize<<<1, 64, 0, stream>>>(g1, b1, S, 1);
        k_rec34<false><<<NBLK, 256, 0, stream>>>(poly, mask, Wpre, W1, W2, Wo1, bo1, Wo2, bo2, S, out);
        k_finalize<<<1, 64, 0, stream>>>(g2, b2, S, 2);
        k_rec34<true><<<NBLK, 256, 0, stream>>>(poly, mask, Wpre, W1, W2, Wo1, bo1, Wo2, bo2, S, out);
    }
}

// Round 7
// 328.972 us; speedup vs baseline: 1.2492x; 1.0340x over previous
//
#include <hip/hip_runtime.h>

#define BN_TOT 24576   // B*N
#define NPTS 786432    // BN_TOT*32
#define EPS_ 1e-5f
#define NBLK 2048
#define TOTW (NBLK * 4)   // fallback path: 8192 waves
#define NB2 1024          // big-ws path: 4 blocks/CU resident when VGPR<=128
#define TOTW2 (NB2 * 4)   // 4096 waves
#define NIT2 (BN_TOT / TOTW2)  // 6 iterations per wave, exact
#define NBO 1024          // out_load: 4 blocks/CU (26KB LDS), 16 waves/CU
#define TOTWO (NBO * 4)   // 4096 waves
#define NITO (BN_TOT / TOTWO)  // 6 iterations per wave, exact

typedef float v4f __attribute__((ext_vector_type(4)));
typedef __attribute__((ext_vector_type(8))) short sv8;    // 8 bf16 (4 VGPRs)
typedef __attribute__((ext_vector_type(4))) float fv4;    // MFMA acc
typedef unsigned short u16;
typedef unsigned int u32;

__device__ __forceinline__ v4f ld4(const float* p) { return *(const v4f*)p; }
__device__ __forceinline__ void st4(float* p, v4f v) { *(v4f*)p = v; }

__device__ __forceinline__ float bf2f(u16 u) {
    union { u32 i; float f; } v; v.i = ((u32)u) << 16; return v.f;
}
__device__ __forceinline__ u32 pack2bf(float a, float b) {   // lo=a, hi=b, RNE
    union { float f; u32 i; } x, y; x.f = a; y.f = b;
    u32 xr = x.i + 0x7FFFu + ((x.i >> 16) & 1u);
    u32 yr = y.i + 0x7FFFu + ((y.i >> 16) & 1u);
    return (xr >> 16) | (yr & 0xFFFF0000u);
}

// Workspace S (floats):
// [128..191] sum2 [192..255] sumsq2 [256..319] sum3 [320..383] sumsq3 [384] cnt (fallback)
// [400..444] M (x xT upper-tri 45) [445..453] sum_x (9) [454] cnt_raw
// [512+L*128 ..] scaleL/shiftL (fallback path only)
// H16 at byte offset 8192, ~100.7 MB, MFMA-NATIVE layout (u16 units per 2048-elem record):
//   value(ch, p) at  (ch>>4)*512 + (p>>4)*256 + ((ch>>2)&3)*64 + (p&15)*4 + (ch&3)
//   writer lane(quad,n) stores uint2 at mt*512 + nt*256 + lane*4 — 512B/wave contiguous.

__global__ void k_finalize(const float* __restrict__ g, const float* __restrict__ b,
                           float* __restrict__ S, int layer) {
    int c = threadIdx.x;
    if (c < 64) {
        float cnt = fmaxf(S[384], 1.f);
        float mean = S[layer * 128 + c] / cnt;
        float var = fmaxf(S[layer * 128 + 64 + c] / cnt - mean * mean, 0.f);
        float sc = g[c] * rsqrtf(var + EPS_);
        float sh = b[c] - mean * sc;
        S[512 + layer * 128 + c] = sc;
        S[512 + layer * 128 + 64 + c] = sh;
    }
}

// ---- moment-based stage-1 stats (R13-proven) -------------------------------
__global__ __launch_bounds__(256) void k_mom(const float* __restrict__ poly,
                                             const int* __restrict__ mask,
                                             float* __restrict__ S) {
    __shared__ float red[4][55];
    const int t = threadIdx.x, wv = t >> 6, lane = t & 63;
    float M[45], sx[9], cc = 0.f;
    #pragma unroll
    for (int i = 0; i < 45; i++) M[i] = 0.f;
    #pragma unroll
    for (int i = 0; i < 9; i++) sx[i] = 0.f;
    for (int idx = blockIdx.x * 256 + t; idx < NPTS; idx += NBLK * 256) {
        float m = (mask[idx] != 0) ? 1.f : 0.f;
        const float* xp = poly + (size_t)idx * 9;
        float x[9];
        #pragma unroll
        for (int j = 0; j < 9; j++) x[j] = xp[j];
        cc += m;
        int k = 0;
        #pragma unroll
        for (int a = 0; a < 9; a++) {
            float xa = x[a] * m;
            sx[a] += xa;
            #pragma unroll
            for (int b2 = a; b2 < 9; b2++) { M[k] += xa * x[b2]; k++; }
        }
    }
    #pragma unroll
    for (int i = 0; i < 45; i++) {
        float v = M[i];
        v += __shfl_xor(v, 1); v += __shfl_xor(v, 2); v += __shfl_xor(v, 4);
        v += __shfl_xor(v, 8); v += __shfl_xor(v, 16); v += __shfl_xor(v, 32);
        M[i] = v;
    }
    #pragma unroll
    for (int i = 0; i < 9; i++) {
        float v = sx[i];
        v += __shfl_xor(v, 1); v += __shfl_xor(v, 2); v += __shfl_xor(v, 4);
        v += __shfl_xor(v, 8); v += __shfl_xor(v, 16); v += __shfl_xor(v, 32);
        sx[i] = v;
    }
    {
        float v = cc;
        v += __shfl_xor(v, 1); v += __shfl_xor(v, 2); v += __shfl_xor(v, 4);
        v += __shfl_xor(v, 8); v += __shfl_xor(v, 16); v += __shfl_xor(v, 32);
        cc = v;
    }
    if (lane == 0) {
        #pragma unroll
        for (int i = 0; i < 45; i++) red[wv][i] = M[i];
        #pragma unroll
        for (int i = 0; i < 9; i++) red[wv][45 + i] = sx[i];
        red[wv][54] = cc;
    }
    __syncthreads();
    if (t < 55) atomicAdd(&S[400 + t], red[0][t] + red[1][t] + red[2][t] + red[3][t]);
}

__global__ void k_finalize_mom(const float* __restrict__ Wpre,
                               const float* __restrict__ g, const float* __restrict__ b,
                               float* __restrict__ S) {
    int c = threadIdx.x;
    if (c < 64) {
        float w[9];
        #pragma unroll
        for (int j = 0; j < 9; j++) w[j] = Wpre[c * 9 + j];
        float cnt = fmaxf(S[454], 1.f);
        float s1 = 0.f;
        #pragma unroll
        for (int j = 0; j < 9; j++) s1 += w[j] * S[445 + j];
        float s2 = 0.f;
        int k = 0;
        #pragma unroll
        for (int a = 0; a < 9; a++)
            #pragma unroll
            for (int b2 = a; b2 < 9; b2++) {
                float mm = S[400 + k];
                s2 += (a == b2) ? w[a] * w[a] * mm : 2.f * w[a] * w[b2] * mm;
                k++;
            }
        float mean = s1 / cnt;
        float var = fmaxf(s2 / cnt - mean * mean, 0.f);
        float sc = g[c] * rsqrtf(var + EPS_);
        float sh = b[c] - mean * sc;
        S[512 + c] = sc;
        S[576 + c] = sh;
        if (c == 0) S[384] = S[454];
    }
}

// ---- shared helpers --------------------------------------------------------
__device__ __forceinline__ void mm_acc(float a[4][8], v4f av, v4f w0, v4f w1) {
    #pragma unroll
    for (int i = 0; i < 4; i++) {
        #pragma unroll
        for (int j = 0; j < 4; j++) {
            a[i][j] += av[i] * w0[j];
            a[i][4 + j] += av[i] * w1[j];
        }
    }
}

__device__ __forceinline__ void tzero(float a[4][8]) {
    #pragma unroll
    for (int i = 0; i < 4; i++)
        #pragma unroll
        for (int j = 0; j < 8; j++) a[i][j] = 0.f;
}

__device__ __forceinline__ void load_x(const float* xg, float* xTw, int lane) {
    for (int e = lane; e < 288; e += 64) {
        float v = xg[e];
        int p = e / 9, c = e - 9 * p;
        xTw[c * 36 + p] = v;
    }
}

__device__ __forceinline__ void stage1(const float* xTw, const float* WpT,
                                       int pg, int cg, float a1[4][8]) {
    tzero(a1);
    #pragma unroll
    for (int k = 0; k < 9; k++) {
        v4f av = ld4(xTw + k * 36 + 4 * pg);
        v4f w0 = ld4(WpT + k * 64 + 8 * cg);
        v4f w1 = ld4(WpT + k * 64 + 8 * cg + 4);
        mm_acc(a1, av, w0, w1);
    }
}

__device__ __forceinline__ void gemv64(const float* actw, const float* WT,
                                       int pg, int cg, float a[4][8]) {
    #pragma unroll 8
    for (int k = 0; k < 64; k++) {
        v4f av = ld4(actw + k * 32 + 4 * (pg ^ (k >> 3)));
        v4f w0 = ld4(WT + k * 64 + 8 * cg);
        v4f w1 = ld4(WT + k * 64 + 8 * cg + 4);
        mm_acc(a, av, w0, w1);
    }
}

__device__ __forceinline__ void bn_store_act(float* actw, const float a[4][8],
                                             const float* sc, const float* sh,
                                             const float m[4], int pg, int cg,
                                             float f[4][8]) {
    #pragma unroll
    for (int j = 0; j < 8; j++) {
        v4f v;
        #pragma unroll
        for (int i = 0; i < 4; i++) {
            float x = fmaxf(a[i][j] * sc[j] + sh[j], 0.f) * m[i];
            v[i] = x; f[i][j] = x;
        }
        st4(actw + (8 * cg + j) * 32 + 4 * (pg ^ cg), v);
    }
}

__device__ __forceinline__ void pool_reduce(const float f[4][8], float pmax[8]) {
    #pragma unroll
    for (int j = 0; j < 8; j++) {
        float v = fmaxf(fmaxf(f[0][j], f[1][j]), fmaxf(f[2][j], f[3][j]));
        v = fmaxf(v, __shfl_xor(v, 8));
        v = fmaxf(v, __shfl_xor(v, 16));
        v = fmaxf(v, __shfl_xor(v, 32));
        pmax[j] = v;
    }
}

__device__ __forceinline__ void qa_glob(const float pmax[8], const float* W1,
                                        float* pbufw, int pg, int cg, float qa[8]) {
    if (pg == 0)
        #pragma unroll
        for (int j = 0; j < 8; j++) pbufw[8 * cg + j] = pmax[j];
    __builtin_amdgcn_wave_barrier();
    #pragma unroll
    for (int j = 0; j < 8; j++) qa[j] = 0.f;
    #pragma unroll 4
    for (int kk = 0; kk < 16; kk++) {
        float p0 = pbufw[4 * kk], p1 = pbufw[4 * kk + 1];
        float p2 = pbufw[4 * kk + 2], p3 = pbufw[4 * kk + 3];
        #pragma unroll
        for (int j = 0; j < 8; j++) {
            v4f w = ld4(W1 + (8 * cg + j) * 128 + 64 + 4 * kk);
            qa[j] += w[0] * p0 + w[1] * p1 + w[2] * p2 + w[3] * p3;
        }
    }
}

__device__ __forceinline__ void stats_acc(const float a[4][8], const float m[4],
                                          float sp[8], float ssp[8]) {
    #pragma unroll
    for (int i = 0; i < 4; i++)
        #pragma unroll
        for (int j = 0; j < 8; j++) {
            float hv = a[i][j] * m[i];
            sp[j] += hv; ssp[j] += hv * a[i][j];
        }
}

__device__ __forceinline__ void stats_flush(float sp[8], float ssp[8],
                                            float (*red_s)[64], float (*red_ss)[64],
                                            float* S, int base, int t, int wv,
                                            int pg, int cg) {
    #pragma unroll
    for (int j = 0; j < 8; j++) {
        float v = sp[j];
        v += __shfl_xor(v, 8); v += __shfl_xor(v, 16); v += __shfl_xor(v, 32);
        sp[j] = v;
        float w = ssp[j];
        w += __shfl_xor(w, 8); w += __shfl_xor(w, 16); w += __shfl_xor(w, 32);
        ssp[j] = w;
    }
    if (pg == 0)
        #pragma unroll
        for (int j = 0; j < 8; j++) { red_s[wv][8 * cg + j] = sp[j]; red_ss[wv][8 * cg + j] = ssp[j]; }
    __syncthreads();
    if (t < 64) {
        atomicAdd(&S[base + t], red_s[0][t] + red_s[1][t] + red_s[2][t] + red_s[3][t]);
        atomicAdd(&S[base + 64 + t], red_ss[0][t] + red_ss[1][t] + red_ss[2][t] + red_ss[3][t]);
    }
}

// ---- pass 2 (big ws): MFMA stage2, W1-frags in LDS, SW-pipelined (R2-proven)
// Stage2 MFMA: A=W1 (K=128), B=[feat;pooled]. Stage1 VALU in B-layout.
// Layouts (HW-validated): A[m=lane&15][k=quad*8+j], B[k=quad*8+j][n=lane&15],
// C: col(n)=lane&15, row(m)=mt*16+quad*4+r.
__global__ __launch_bounds__(256) void k_stats2_mfma(const float* __restrict__ poly,
                                                     const int* __restrict__ mask,
                                                     const float* __restrict__ Wpre,
                                                     const float* __restrict__ gpre,
                                                     const float* __restrict__ bpre,
                                                     const float* __restrict__ W1,
                                                     float* __restrict__ S,
                                                     u16* __restrict__ H16) {
    __shared__ __align__(16) float WpT[576];
    __shared__ __align__(16) float xT[4][324];
    __shared__ float scsh[128];
    __shared__ float red_s[4][64], red_ss[4][64];
    __shared__ __align__(16) uint4 awl[16 * 64];   // 16KB: W1 A-frags, lane-ordered
    const int t = threadIdx.x, wv = t >> 6, lane = t & 63;
    const int n = lane & 15, quad = lane >> 4;
    for (int i = t; i < 576; i += 256) { int c = i >> 6, ch = i & 63; WpT[i] = Wpre[ch * 9 + c]; }

    // inline BN1 finalize from moments (cold preamble)
    if (t < 64) {
        float w[9];
        #pragma unroll
        for (int j = 0; j < 9; j++) w[j] = Wpre[t * 9 + j];
        float cnt = fmaxf(S[454], 1.f);
        float s1 = 0.f;
        #pragma unroll
        for (int j = 0; j < 9; j++) s1 += w[j] * S[445 + j];
        float s2 = 0.f;
        int k = 0;
        #pragma unroll
        for (int a = 0; a < 9; a++)
            #pragma unroll
            for (int b2 = a; b2 < 9; b2++) {
                float mm = S[400 + k];
                s2 += (a == b2) ? w[a] * w[a] * mm : 2.f * w[a] * w[b2] * mm;
                k++;
            }
        float mean = s1 / cnt;
        float var = fmaxf(s2 / cnt - mean * mean, 0.f);
        float sc = gpre[t] * rsqrtf(var + EPS_);
        scsh[t] = sc;
        scsh[64 + t] = bpre[t] - mean * sc;
    }

    // build shared A-fragment table: wave wv packs mt=wv (frag depends only on lane)
    #pragma unroll
    for (int ss = 0; ss < 4; ss++) {
        const float* wr = W1 + (size_t)(wv * 16 + n) * 128 + ss * 32 + quad * 8;
        union { uint4 q; u32 w[4]; } uu;
        #pragma unroll
        for (int d = 0; d < 4; d++) uu.w[d] = pack2bf(wr[2 * d], wr[2 * d + 1]);
        awl[(wv * 4 + ss) * 64 + lane] = uu.q;
    }
    __syncthreads();
    float sck[16], shk[16];
    #pragma unroll
    for (int s = 0; s < 2; s++)
        #pragma unroll
        for (int j = 0; j < 8; j++) {
            int c = s * 32 + quad * 8 + j;
            sck[s * 8 + j] = scsh[c];
            shk[s * 8 + j] = scsh[64 + c];
        }

    float sp16[16], ssp16[16];
    #pragma unroll
    for (int e = 0; e < 16; e++) { sp16[e] = 0.f; ssp16[e] = 0.f; }

    // loop-invariant transpose-scatter addresses (e/9 hoisted out of the loop)
    int ax0, ax1, ax2, ax3, ax4;
    {
        int e = lane;        int p = e / 9; ax0 = (e - 9 * p) * 36 + p;
        e = lane + 64;       p = e / 9;     ax1 = (e - 9 * p) * 36 + p;
        e = lane + 128;      p = e / 9;     ax2 = (e - 9 * p) * 36 + p;
        e = lane + 192;      p = e / 9;     ax3 = (e - 9 * p) * 36 + p;
        e = lane + 256;      p = e / 9;     ax4 = (e - 9 * p) * 36 + p;
    }

    const sv8* awp = (const sv8*)awl;
    const int wgid = blockIdx.x * 4 + wv;
    // prologue prefetch: polyline wgid
    float xr0, xr1, xr2, xr3, xr4, mvr;
    {
        const float* xg = poly + (size_t)wgid * 288;
        xr0 = xg[lane]; xr1 = xg[lane + 64]; xr2 = xg[lane + 128]; xr3 = xg[lane + 192];
        xr4 = (lane < 32) ? xg[256 + lane] : 0.f;
        mvr = (lane < 32 && mask[wgid * 32 + lane] != 0) ? 1.f : 0.f;
    }

    for (int it = 0; it < NIT2; it++) {
        const int bn = wgid + it * TOTW2;
        const float mv = mvr;
        // scatter prefetched x into per-wave LDS tile
        xT[wv][ax0] = xr0; xT[wv][ax1] = xr1; xT[wv][ax2] = xr2; xT[wv][ax3] = xr3;
        if (lane < 32) xT[wv][ax4] = xr4;
        __builtin_amdgcn_wave_barrier();
        // issue next polyline's loads; latency hides under this iteration's compute
        if (it < NIT2 - 1) {
            const int bnn = bn + TOTW2;
            const float* xg = poly + (size_t)bnn * 288;
            xr0 = xg[lane]; xr1 = xg[lane + 64]; xr2 = xg[lane + 128]; xr3 = xg[lane + 192];
            if (lane < 32) {
                xr4 = xg[256 + lane];
                mvr = (mask[bnn * 32 + lane] != 0) ? 1.f : 0.f;
            }
        }
        // stage1 (VALU) for points {n, 16+n}, channels {s*32+quad*8+j}
        float f0[16], f1[16];
        #pragma unroll
        for (int e = 0; e < 16; e++) { f0[e] = 0.f; f1[e] = 0.f; }
        #pragma unroll
        for (int k = 0; k < 9; k++) {
            float x0 = xT[wv][k * 36 + n];
            float x1 = xT[wv][k * 36 + 16 + n];
            v4f wA0 = ld4(WpT + k * 64 + quad * 8);
            v4f wA1 = ld4(WpT + k * 64 + quad * 8 + 4);
            v4f wB0 = ld4(WpT + k * 64 + 32 + quad * 8);
            v4f wB1 = ld4(WpT + k * 64 + 32 + quad * 8 + 4);
            #pragma unroll
            for (int j = 0; j < 4; j++) {
                f0[j] += x0 * wA0[j];  f0[4 + j] += x0 * wA1[j];
                f0[8 + j] += x0 * wB0[j]; f0[12 + j] += x0 * wB1[j];
                f1[j] += x1 * wA0[j];  f1[4 + j] += x1 * wA1[j];
                f1[8 + j] += x1 * wB0[j]; f1[12 + j] += x1 * wB1[j];
            }
        }
        float mp0 = __shfl(mv, n), mp1 = __shfl(mv, 16 + n);
        #pragma unroll
        for (int e = 0; e < 16; e++) {
            f0[e] = fmaxf(f0[e] * sck[e] + shk[e], 0.f) * mp0;
            f1[e] = fmaxf(f1[e] * sck[e] + shk[e], 0.f) * mp1;
        }
        float pm[16];
        #pragma unroll
        for (int e = 0; e < 16; e++) {
            float v = fmaxf(f0[e], f1[e]);
            v = fmaxf(v, __shfl_xor(v, 1));
            v = fmaxf(v, __shfl_xor(v, 2));
            v = fmaxf(v, __shfl_xor(v, 4));
            v = fmaxf(v, __shfl_xor(v, 8));
            pm[e] = v;
        }
        sv8 bg0[2], bg1[2], bp[2];
        #pragma unroll
        for (int s = 0; s < 2; s++) {
            union { sv8 v; u32 w[4]; } a, b, c;
            #pragma unroll
            for (int d = 0; d < 4; d++) {
                a.w[d] = pack2bf(f0[s * 8 + 2 * d], f0[s * 8 + 2 * d + 1]);
                b.w[d] = pack2bf(f1[s * 8 + 2 * d], f1[s * 8 + 2 * d + 1]);
                c.w[d] = pack2bf(pm[s * 8 + 2 * d], pm[s * 8 + 2 * d + 1]);
            }
            bg0[s] = a.v; bg1[s] = b.v; bp[s] = c.v;
        }
        // per-mt MFMA: A-frags from LDS (short-lived), acc dies after stats+store
        u16* Hw = H16 + (size_t)bn * 2048;
        #pragma unroll
        for (int mt = 0; mt < 4; mt++) {
            sv8 a0 = awp[(mt * 4 + 0) * 64 + lane];
            sv8 a1 = awp[(mt * 4 + 1) * 64 + lane];
            sv8 a2 = awp[(mt * 4 + 2) * 64 + lane];
            sv8 a3 = awp[(mt * 4 + 3) * 64 + lane];
            fv4 c0 = {0.f, 0.f, 0.f, 0.f}, c1 = {0.f, 0.f, 0.f, 0.f};
            c0 = __builtin_amdgcn_mfma_f32_16x16x32_bf16(a0, bg0[0], c0, 0, 0, 0);
            c0 = __builtin_amdgcn_mfma_f32_16x16x32_bf16(a1, bg0[1], c0, 0, 0, 0);
            c0 = __builtin_amdgcn_mfma_f32_16x16x32_bf16(a2, bp[0], c0, 0, 0, 0);
            c0 = __builtin_amdgcn_mfma_f32_16x16x32_bf16(a3, bp[1], c0, 0, 0, 0);
            c1 = __builtin_amdgcn_mfma_f32_16x16x32_bf16(a0, bg1[0], c1, 0, 0, 0);
            c1 = __builtin_amdgcn_mfma_f32_16x16x32_bf16(a1, bg1[1], c1, 0, 0, 0);
            c1 = __builtin_amdgcn_mfma_f32_16x16x32_bf16(a2, bp[0], c1, 0, 0, 0);
            c1 = __builtin_amdgcn_mfma_f32_16x16x32_bf16(a3, bp[1], c1, 0, 0, 0);
            #pragma unroll
            for (int r = 0; r < 4; r++) {
                sp16[mt * 4 + r] += c0[r] * mp0 + c1[r] * mp1;
                ssp16[mt * 4 + r] += c0[r] * c0[r] * mp0 + c1[r] * c1[r] * mp1;
            }
            uint2 pk0, pk1;
            pk0.x = pack2bf(c0[0], c0[1]); pk0.y = pack2bf(c0[2], c0[3]);
            pk1.x = pack2bf(c1[0], c1[1]); pk1.y = pack2bf(c1[2], c1[3]);
            *(uint2*)(Hw + mt * 512 + lane * 4) = pk0;
            *(uint2*)(Hw + mt * 512 + 256 + lane * 4) = pk1;
        }
        __builtin_amdgcn_wave_barrier();
    }
    #pragma unroll
    for (int e = 0; e < 16; e++) {
        float v = sp16[e];
        v += __shfl_xor(v, 1); v += __shfl_xor(v, 2); v += __shfl_xor(v, 4); v += __shfl_xor(v, 8);
        sp16[e] = v;
        float w = ssp16[e];
        w += __shfl_xor(w, 1); w += __shfl_xor(w, 2); w += __shfl_xor(w, 4); w += __shfl_xor(w, 8);
        ssp16[e] = w;
    }
    if (n == 0) {
        #pragma unroll
        for (int mt = 0; mt < 4; mt++)
            #pragma unroll
            for (int r = 0; r < 4; r++) {
                red_s[wv][mt * 16 + quad * 4 + r] = sp16[mt * 4 + r];
                red_ss[wv][mt * 16 + quad * 4 + r] = ssp16[mt * 4 + r];
            }
    }
    __syncthreads();
    if (t < 64) {
        atomicAdd(&S[128 + t], red_s[0][t] + red_s[1][t] + red_s[2][t] + red_s[3][t]);
        atomicAdd(&S[128 + 64 + t], red_ss[0][t] + red_ss[1][t] + red_ss[2][t] + red_ss[3][t]);
    }
}

// ---- pass 3 (big ws): MFMA-native H16 in/out, W2-frags in LDS --------------
__global__ __launch_bounds__(256) void k_stats3_mfma(const int* __restrict__ mask,
                                                     const float* __restrict__ g1,
                                                     const float* __restrict__ b1,
                                                     const float* __restrict__ W2,
                                                     float* __restrict__ S,
                                                     u16* __restrict__ H16) {
    __shared__ float scsh[128];
    __shared__ float red_s[4][64], red_ss[4][64];
    __shared__ __align__(16) uint4 awl[8 * 64];   // 8KB: W2 A-frags, lane-ordered
    const int t = threadIdx.x, wv = t >> 6, lane = t & 63;
    const int n = lane & 15, quad = lane >> 4;

    if (t < 64) {
        float cnt = fmaxf(S[454], 1.f);
        float mean = S[128 + t] / cnt;
        float var = fmaxf(S[192 + t] / cnt - mean * mean, 0.f);
        float sc = g1[t] * rsqrtf(var + EPS_);
        scsh[t] = sc;
        scsh[64 + t] = b1[t] - mean * sc;
    }

    #pragma unroll
    for (int s = 0; s < 2; s++) {
        const float* wr = W2 + (wv * 16 + n) * 64 + s * 32 + quad * 8;
        union { uint4 q; u32 w[4]; } uu;
        #pragma unroll
        for (int d = 0; d < 4; d++) uu.w[d] = pack2bf(wr[2 * d], wr[2 * d + 1]);
        awl[(wv * 2 + s) * 64 + lane] = uu.q;
    }
    __syncthreads();
    float sck[16], shk[16];
    #pragma unroll
    for (int s = 0; s < 2; s++)
        #pragma unroll
        for (int j = 0; j < 8; j++) {
            int k = s * 32 + quad * 8 + j;
            sck[s * 8 + j] = scsh[k];
            shk[s * 8 + j] = scsh[64 + k];
        }

    float sp16[16], ssp16[16];
    #pragma unroll
    for (int e = 0; e < 16; e++) { sp16[e] = 0.f; ssp16[e] = 0.f; }

    const sv8* awp = (const sv8*)awl;
    const int wgid = blockIdx.x * 4 + wv;
    // reader offset for B-fragment gather: ch = s*32+quad*8+j ->
    //   mt' = s*2+(quad>>1), quad'_base = (quad&1)*2 (+ j>>2), r = j&3
    const int hoff = (quad >> 1) * 512 + (quad & 1) * 128 + n * 4;
    uint2 hr[2][2][2];   // [nt][s][half]
    float mvr;
    {
        const u16* Hb = H16 + (size_t)wgid * 2048;
        #pragma unroll
        for (int nt = 0; nt < 2; nt++)
            #pragma unroll
            for (int s = 0; s < 2; s++)
                #pragma unroll
                for (int h = 0; h < 2; h++)
                    hr[nt][s][h] = *(const uint2*)(Hb + hoff + s * 1024 + nt * 256 + h * 64);
        mvr = (lane < 32 && mask[wgid * 32 + lane] != 0) ? 1.f : 0.f;
    }

    for (int it = 0; it < NIT2; it++) {
        const int bn = wgid + it * TOTW2;
        const float mv = mvr;
        float mpn[2] = {__shfl(mv, n), __shfl(mv, 16 + n)};
        sv8 bg[2][2];
        #pragma unroll
        for (int nt = 0; nt < 2; nt++)
            #pragma unroll
            for (int s = 0; s < 2; s++) {
                u32 ws[4] = {hr[nt][s][0].x, hr[nt][s][0].y, hr[nt][s][1].x, hr[nt][s][1].y};
                union { sv8 v; u32 w[4]; } uu;
                #pragma unroll
                for (int d = 0; d < 4; d++) {
                    union { u32 u; float f; } lo, hi;
                    lo.u = ws[d] << 16; hi.u = ws[d] & 0xFFFF0000u;
                    float g0 = fmaxf(lo.f * sck[s * 8 + 2 * d] + shk[s * 8 + 2 * d], 0.f) * mpn[nt];
                    float g1v = fmaxf(hi.f * sck[s * 8 + 2 * d + 1] + shk[s * 8 + 2 * d + 1], 0.f) * mpn[nt];
                    uu.w[d] = pack2bf(g0, g1v);
                }
                bg[nt][s] = uu.v;
            }
        // prefetch next polyline's h1 fragments (hr fully consumed above)
        if (it < NIT2 - 1) {
            const int bnn = bn + TOTW2;
            const u16* Hb = H16 + (size_t)bnn * 2048;
            #pragma unroll
            for (int nt = 0; nt < 2; nt++)
                #pragma unroll
                for (int s = 0; s < 2; s++)
                    #pragma unroll
                    for (int h = 0; h < 2; h++)
                        hr[nt][s][h] = *(const uint2*)(Hb + hoff + s * 1024 + nt * 256 + h * 64);
            if (lane < 32) mvr = (mask[bnn * 32 + lane] != 0) ? 1.f : 0.f;
        }
        u16* Hw = H16 + (size_t)bn * 2048;
        #pragma unroll
        for (int nt = 0; nt < 2; nt++) {
            float mp = mpn[nt];
            #pragma unroll
            for (int mt = 0; mt < 4; mt++) {
                sv8 a0 = awp[(mt * 2 + 0) * 64 + lane];
                sv8 a1 = awp[(mt * 2 + 1) * 64 + lane];
                fv4 c = {0.f, 0.f, 0.f, 0.f};
                c = __builtin_amdgcn_mfma_f32_16x16x32_bf16(a0, bg[nt][0], c, 0, 0, 0);
                c = __builtin_amdgcn_mfma_f32_16x16x32_bf16(a1, bg[nt][1], c, 0, 0, 0);
                #pragma unroll
                for (int r = 0; r < 4; r++) {
                    sp16[mt * 4 + r] += c[r] * mp;
                    ssp16[mt * 4 + r] += c[r] * c[r] * mp;
                }
                uint2 pk;
                pk.x = pack2bf(c[0], c[1]);
                pk.y = pack2bf(c[2], c[3]);
                *(uint2*)(Hw + mt * 512 + nt * 256 + lane * 4) = pk;
            }
        }
    }
    #pragma unroll
    for (int e = 0; e < 16; e++) {
        float v = sp16[e];
        v += __shfl_xor(v, 1); v += __shfl_xor(v, 2); v += __shfl_xor(v, 4); v += __shfl_xor(v, 8);
        sp16[e] = v;
        float w = ssp16[e];
        w += __shfl_xor(w, 1); w += __shfl_xor(w, 2); w += __shfl_xor(w, 4); w += __shfl_xor(w, 8);
        ssp16[e] = w;
    }
    if (n == 0) {
        #pragma unroll
        for (int mt = 0; mt < 4; mt++)
            #pragma unroll
            for (int r = 0; r < 4; r++) {
                red_s[wv][mt * 16 + quad * 4 + r] = sp16[mt * 4 + r];
                red_ss[wv][mt * 16 + quad * 4 + r] = ssp16[mt * 4 + r];
            }
    }
    __syncthreads();
    if (t < 64) {
        atomicAdd(&S[256 + t], red_s[0][t] + red_s[1][t] + red_s[2][t] + red_s[3][t]);
        atomicAdd(&S[256 + 64 + t], red_ss[0][t] + red_ss[1][t] + red_ss[2][t] + red_ss[3][t]);
    }
}

// ---- pass 4 (big ws): H16 read + bf16-packed Wo1/Wo2 in LDS (26KB, 4 blk/CU)
__global__ __launch_bounds__(256) void k_out_load(const int* __restrict__ mask,
                                                  const float* __restrict__ g2,
                                                  const float* __restrict__ b2,
                                                  const float* __restrict__ Wo1,
                                                  const float* __restrict__ bo1,
                                                  const float* __restrict__ Wo2,
                                                  const float* __restrict__ bo2,
                                                  const float* __restrict__ S,
                                                  const u16* __restrict__ H16,
                                                  float* __restrict__ out) {
    __shared__ __align__(16) u32 Wo1p[2048];   // 8KB:  [kk*64+ch]  = bf16(w[2kk],w[2kk+1])
    __shared__ __align__(16) u32 Wo2p[4096];   // 16KB: [kk*128+o] = bf16(w[2kk],w[2kk+1])
    __shared__ float pbuf[4][64];
    __shared__ float scsh[128];
    const int t = threadIdx.x, wv = t >> 6, lane = t & 63;
    const int n = lane & 15, quad = lane >> 4;
    if (t < 64) {
        float cnt = fmaxf(S[454], 1.f);
        float mean = S[256 + t] / cnt;
        float var = fmaxf(S[320 + t] / cnt - mean * mean, 0.f);
        float sc = g2[t] * rsqrtf(var + EPS_);
        scsh[t] = sc;
        scsh[64 + t] = b2[t] - mean * sc;
    }
    for (int i = t; i < 2048; i += 256) {
        int kk = i >> 6, ch = i & 63;
        Wo1p[i] = pack2bf(Wo1[ch * 64 + 2 * kk], Wo1[ch * 64 + 2 * kk + 1]);
    }
    for (int i = t; i < 4096; i += 256) {
        int kk = i >> 7, o = i & 127;
        Wo2p[i] = pack2bf(Wo2[o * 64 + 2 * kk], Wo2[o * 64 + 2 * kk + 1]);
    }
    __syncthreads();
    float sc3[16], sh3[16];
    #pragma unroll
    for (int mt = 0; mt < 4; mt++)
        #pragma unroll
        for (int r = 0; r < 4; r++) {
            sc3[mt * 4 + r] = scsh[mt * 16 + quad * 4 + r];
            sh3[mt * 4 + r] = scsh[64 + mt * 16 + quad * 4 + r];
        }
    float bo1v = bo1[lane], bo2a = bo2[lane], bo2b = bo2[64 + lane];
    const int wgid = blockIdx.x * 4 + wv;
    uint2 hr[4][2];   // [mt][nt]
    float mvr;
    {
        const u16* Hb = H16 + (size_t)wgid * 2048;
        #pragma unroll
        for (int mt = 0; mt < 4; mt++)
            #pragma unroll
            for (int nt = 0; nt < 2; nt++)
                hr[mt][nt] = *(const uint2*)(Hb + mt * 512 + nt * 256 + lane * 4);
        mvr = (lane < 32 && mask[wgid * 32 + lane] != 0) ? 1.f : 0.f;
    }
    for (int it = 0; it < NITO; it++) {
        const int bn = wgid + it * TOTWO;
        const float mv = mvr;
        float mpn[2] = {__shfl(mv, n), __shfl(mv, 16 + n)};
        float vf = __ballot(mv > 0.5f) ? 1.f : 0.f;
        float pm[16];
        #pragma unroll
        for (int mt = 0; mt < 4; mt++)
            #pragma unroll
            for (int nt = 0; nt < 2; nt++) {
                u32 wx = hr[mt][nt].x, wy = hr[mt][nt].y;
                float v0 = bf2f((u16)(wx & 0xFFFFu)), v1 = bf2f((u16)(wx >> 16));
                float v2 = bf2f((u16)(wy & 0xFFFFu)), v3 = bf2f((u16)(wy >> 16));
                float mp = mpn[nt];
                float e0 = fmaxf(v0 * sc3[mt * 4 + 0] + sh3[mt * 4 + 0], 0.f) * mp;
                float e1 = fmaxf(v1 * sc3[mt * 4 + 1] + sh3[mt * 4 + 1], 0.f) * mp;
                float e2 = fmaxf(v2 * sc3[mt * 4 + 2] + sh3[mt * 4 + 2], 0.f) * mp;
                float e3 = fmaxf(v3 * sc3[mt * 4 + 3] + sh3[mt * 4 + 3], 0.f) * mp;
                if (nt == 0) {
                    pm[mt * 4 + 0] = e0; pm[mt * 4 + 1] = e1;
                    pm[mt * 4 + 2] = e2; pm[mt * 4 + 3] = e3;
                } else {
                    pm[mt * 4 + 0] = fmaxf(pm[mt * 4 + 0], e0);
                    pm[mt * 4 + 1] = fmaxf(pm[mt * 4 + 1], e1);
                    pm[mt * 4 + 2] = fmaxf(pm[mt * 4 + 2], e2);
                    pm[mt * 4 + 3] = fmaxf(pm[mt * 4 + 3], e3);
                }
            }
        if (it < NITO - 1) {
            const int bnn = bn + TOTWO;
            const u16* Hb = H16 + (size_t)bnn * 2048;
            #pragma unroll
            for (int mt = 0; mt < 4; mt++)
                #pragma unroll
                for (int nt = 0; nt < 2; nt++)
                    hr[mt][nt] = *(const uint2*)(Hb + mt * 512 + nt * 256 + lane * 4);
            if (lane < 32) mvr = (mask[bnn * 32 + lane] != 0) ? 1.f : 0.f;
        }
        #pragma unroll
        for (int e = 0; e < 16; e++) {
            float v = pm[e];
            v = fmaxf(v, __shfl_xor(v, 1));
            v = fmaxf(v, __shfl_xor(v, 2));
            v = fmaxf(v, __shfl_xor(v, 4));
            v = fmaxf(v, __shfl_xor(v, 8));
            pm[e] = v;
        }
        if (n == 0) {
            #pragma unroll
            for (int mt = 0; mt < 4; mt++)
                #pragma unroll
                for (int r = 0; r < 4; r++)
                    pbuf[wv][mt * 16 + quad * 4 + r] = pm[mt * 4 + r];
        }
        __builtin_amdgcn_wave_barrier();
        float y1 = bo1v;
        #pragma unroll 8
        for (int kk = 0; kk < 32; kk++) {
            u32 w = Wo1p[kk * 64 + lane];
            union { u32 u; float f; } lo, hi;
            lo.u = w << 16; hi.u = w & 0xFFFF0000u;
            y1 += lo.f * pbuf[wv][2 * kk] + hi.f * pbuf[wv][2 * kk + 1];
        }
        y1 = fmaxf(y1, 0.f);
        pbuf[wv][lane] = y1;
        __builtin_amdgcn_wave_barrier();
        float o0 = bo2a, o1 = bo2b;
        #pragma unroll 8
        for (int kk = 0; kk < 32; kk++) {
            float p0 = pbuf[wv][2 * kk], p1 = pbuf[wv][2 * kk + 1];
            u32 wa = Wo2p[kk * 128 + lane];
            u32 wb = Wo2p[kk * 128 + 64 + lane];
            union { u32 u; float f; } la, ha, lb, hb;
            la.u = wa << 16; ha.u = wa & 0xFFFF0000u;
            lb.u = wb << 16; hb.u = wb & 0xFFFF0000u;
            o0 += la.f * p0 + ha.f * p1;
            o1 += lb.f * p0 + hb.f * p1;
        }
        out[(size_t)bn * 128 + lane] = o0 * vf;
        out[(size_t)bn * 128 + 64 + lane] = o1 * vf;
        __builtin_amdgcn_wave_barrier();
    }
}

// ---- fallback (small ws): recompute path, untouched ------------------------
__device__ __forceinline__ void qa_lds_fb(const float pmax[8], const float* W1pT,
                                          int cg, float qa[8]) {
    #pragma unroll
    for (int j = 0; j < 8; j++) qa[j] = 0.f;
    #pragma unroll
    for (int k = 0; k < 64; k++) {
        float pv = __shfl(pmax[k & 7], k >> 3);
        v4f w0 = ld4(W1pT + k * 64 + 8 * cg);
        v4f w1 = ld4(W1pT + k * 64 + 8 * cg + 4);
        #pragma unroll
        for (int j = 0; j < 4; j++) { qa[j] += pv * w0[j]; qa[4 + j] += pv * w1[j]; }
    }
}

__global__ __launch_bounds__(256) void k_stats2_fb(const float* __restrict__ poly,
                                                   const int* __restrict__ mask,
                                                   const float* __restrict__ Wpre,
                                                   const float* __restrict__ W1,
                                                   float* __restrict__ S) {
    __shared__ __align__(16) float WpT[576];
    __shared__ __align__(16) float W1aT[4096];
    __shared__ __align__(16) float W1pT[4096];
    __shared__ __align__(16) float act[4][2048];
    __shared__ __align__(16) float xT[4][324];
    __shared__ float red_s[4][64], red_ss[4][64];
    const int t = threadIdx.x, wv = t >> 6, lane = t & 63;
    const int pg = lane >> 3, cg = lane & 7;
    for (int i = t; i < 576; i += 256) { int c = i >> 6, ch = i & 63; WpT[i] = Wpre[ch * 9 + c]; }
    for (int i = t; i < 4096; i += 256) {
        int k = i >> 6, ch = i & 63;
        W1aT[i] = W1[ch * 128 + k];
        W1pT[i] = W1[ch * 128 + 64 + k];
    }
    __syncthreads();
    float sc1[8], sh1[8];
    #pragma unroll
    for (int j = 0; j < 8; j++) { sc1[j] = S[512 + 8 * cg + j]; sh1[j] = S[576 + 8 * cg + j]; }
    float sp[8] = {0}, ssp[8] = {0};
    const int wgid = blockIdx.x * 4 + wv;
    for (int bn = wgid; bn < BN_TOT; bn += TOTW) {
        float mv = (lane < 32 && mask[bn * 32 + lane] != 0) ? 1.f : 0.f;
        float m[4];
        #pragma unroll
        for (int i = 0; i < 4; i++) m[i] = __shfl(mv, 4 * pg + i);
        load_x(poly + (size_t)bn * 288, xT[wv], lane);
        __builtin_amdgcn_wave_barrier();
        float a1[4][8], f[4][8];
        stage1(xT[wv], WpT, pg, cg, a1);
        bn_store_act(act[wv], a1, sc1, sh1, m, pg, cg, f);
        float pmax[8], qa[8];
        pool_reduce(f, pmax);
        qa_lds_fb(pmax, W1pT, cg, qa);
        __builtin_amdgcn_wave_barrier();
        float a2[4][8];
        #pragma unroll
        for (int i = 0; i < 4; i++)
            #pragma unroll
            for (int j = 0; j < 8; j++) a2[i][j] = qa[j];
        gemv64(act[wv], W1aT, pg, cg, a2);
        stats_acc(a2, m, sp, ssp);
        __builtin_amdgcn_wave_barrier();
    }
    stats_flush(sp, ssp, red_s, red_ss, S, 128, t, wv, pg, cg);
}

template<bool DO_OUT>
__global__ __launch_bounds__(256) void k_rec34(const float* __restrict__ poly,
                                               const int* __restrict__ mask,
                                               const float* __restrict__ Wpre,
                                               const float* __restrict__ W1,
                                               const float* __restrict__ W2,
                                               const float* __restrict__ Wo1,
                                               const float* __restrict__ bo1,
                                               const float* __restrict__ Wo2,
                                               const float* __restrict__ bo2,
                                               float* __restrict__ S,
                                               float* __restrict__ out) {
    __shared__ __align__(16) float WpT[576];
    __shared__ __align__(16) float W1aT[4096];
    __shared__ __align__(16) float W2T[4096];
    __shared__ __align__(16) float act[4][2048];
    __shared__ __align__(16) float xT[4][324];
    __shared__ float pbuf[4][64];
    __shared__ float red_s[4][64], red_ss[4][64];
    const int t = threadIdx.x, wv = t >> 6, lane = t & 63;
    const int pg = lane >> 3, cg = lane & 7;
    for (int i = t; i < 576; i += 256) { int c = i >> 6, ch = i & 63; WpT[i] = Wpre[ch * 9 + c]; }
    for (int i = t; i < 4096; i += 256) {
        int k = i >> 6, ch = i & 63;
        W1aT[i] = W1[ch * 128 + k];
        W2T[i] = W2[ch * 64 + k];
    }
    __syncthreads();
    float sc1[8], sh1[8], sc2[8], sh2[8], sc3[8], sh3[8];
    #pragma unroll
    for (int j = 0; j < 8; j++) {
        sc1[j] = S[512 + 8 * cg + j]; sh1[j] = S[576 + 8 * cg + j];
        sc2[j] = S[640 + 8 * cg + j]; sh2[j] = S[704 + 8 * cg + j];
    }
    if constexpr (DO_OUT)
        #pragma unroll
        for (int j = 0; j < 8; j++) { sc3[j] = S[768 + 8 * cg + j]; sh3[j] = S[832 + 8 * cg + j]; }
    float bo1v = 0.f, bo2a = 0.f, bo2b = 0.f;
    if constexpr (DO_OUT) { bo1v = bo1[lane]; bo2a = bo2[lane]; bo2b = bo2[64 + lane]; }
    float sp[8] = {0}, ssp[8] = {0};
    const int wgid = blockIdx.x * 4 + wv;
    for (int bn = wgid; bn < BN_TOT; bn += TOTW) {
        float mv = (lane < 32 && mask[bn * 32 + lane] != 0) ? 1.f : 0.f;
        float m[4];
        #pragma unroll
        for (int i = 0; i < 4; i++) m[i] = __shfl(mv, 4 * pg + i);
        load_x(poly + (size_t)bn * 288, xT[wv], lane);
        __builtin_amdgcn_wave_barrier();
        float a1[4][8], f[4][8];
        stage1(xT[wv], WpT, pg, cg, a1);
        bn_store_act(act[wv], a1, sc1, sh1, m, pg, cg, f);
        float pmax[8], qa[8];
        pool_reduce(f, pmax);
        qa_glob(pmax, W1, pbuf[wv], pg, cg, qa);
        __builtin_amdgcn_wave_barrier();
        float a2[4][8];
        #pragma unroll
        for (int i = 0; i < 4; i++)
            #pragma unroll
            for (int j = 0; j < 8; j++) a2[i][j] = qa[j];
        gemv64(act[wv], W1aT, pg, cg, a2);
        __builtin_amdgcn_wave_barrier();
        bn_store_act(act[wv], a2, sc2, sh2, m, pg, cg, f);
        __builtin_amdgcn_wave_barrier();
        float a3[4][8];
        tzero(a3);
        gemv64(act[wv], W2T, pg, cg, a3);
        if constexpr (!DO_OUT) {
            stats_acc(a3, m, sp, ssp);
        } else {
            float px[8];
            #pragma unroll
            for (int j = 0; j < 8; j++) {
                float v = 0.f;
                #pragma unroll
                for (int i = 0; i < 4; i++)
                    v = fmaxf(v, fmaxf(a3[i][j] * sc3[j] + sh3[j], 0.f) * m[i]);
                px[j] = v;
            }
            #pragma unroll
            for (int j = 0; j < 8; j++) {
                float v = px[j];
                v = fmaxf(v, __shfl_xor(v, 8));
                v = fmaxf(v, __shfl_xor(v, 16));
                v = fmaxf(v, __shfl_xor(v, 32));
                px[j] = v;
            }
            if (pg == 0)
                #pragma unroll
                for (int j = 0; j < 8; j++) pbuf[wv][8 * cg + j] = px[j];
            __builtin_amdgcn_wave_barrier();
            float y1 = bo1v;
            #pragma unroll 4
            for (int kk = 0; kk < 16; kk++) {
                v4f w = ld4(Wo1 + lane * 64 + 4 * kk);
                y1 += w[0] * pbuf[wv][4 * kk] + w[1] * pbuf[wv][4 * kk + 1]
                    + w[2] * pbuf[wv][4 * kk + 2] + w[3] * pbuf[wv][4 * kk + 3];
            }
            y1 = fmaxf(y1, 0.f);
            pbuf[wv][lane] = y1;
            __builtin_amdgcn_wave_barrier();
            float o0 = bo2a, o1 = bo2b;
            #pragma unroll 4
            for (int kk = 0; kk < 16; kk++) {
                v4f w0 = ld4(Wo2 + lane * 64 + 4 * kk);
                v4f w1 = ld4(Wo2 + (64 + lane) * 64 + 4 * kk);
                float p0 = pbuf[wv][4 * kk], p1 = pbuf[wv][4 * kk + 1];
                float p2 = pbuf[wv][4 * kk + 2], p3 = pbuf[wv][4 * kk + 3];
                o0 += w0[0] * p0 + w0[1] * p1 + w0[2] * p2 + w0[3] * p3;
                o1 += w1[0] * p0 + w1[1] * p1 + w1[2] * p2 + w1[3] * p3;
            }
            float vf = __ballot(mv > 0.5f) ? 1.f : 0.f;
            out[(size_t)bn * 128 + lane] = o0 * vf;
            out[(size_t)bn * 128 + 64 + lane] = o1 * vf;
        }
        __builtin_amdgcn_wave_barrier();
    }
    if constexpr (!DO_OUT)
        stats_flush(sp, ssp, red_s, red_ss, S, 256, t, wv, pg, cg);
}

extern "C" void kernel_launch(void* const* d_in, const int* in_sizes, int n_in,
                              void* d_out, int out_size, void* d_ws, size_t ws_size,
                              hipStream_t stream) {
    const float* poly = (const float*)d_in[0];
    const int*   mask = (const int*)d_in[1];
    const float* Wpre = (const float*)d_in[2];
    const float* gpre = (const float*)d_in[3];
    const float* bpre = (const float*)d_in[4];
    const float* W1   = (const float*)d_in[5];
    const float* g1   = (const float*)d_in[6];
    const float* b1   = (const float*)d_in[7];
    const float* W2   = (const float*)d_in[8];
    const float* g2   = (const float*)d_in[9];
    const float* b2   = (const float*)d_in[10];
    const float* Wo1  = (const float*)d_in[11];
    const float* bo1  = (const float*)d_in[12];
    const float* Wo2  = (const float*)d_in[13];
    const float* bo2  = (const float*)d_in[14];

    float* S = (float*)d_ws;
    u16* H16 = (u16*)((char*)d_ws + 8192);
    float* out = (float*)d_out;

    const size_t needWS = 8192 + (size_t)BN_TOT * 2048 * sizeof(u16);  // ~100.7 MB

    hipMemsetAsync(S, 0, 512 * sizeof(float), stream);
    k_mom<<<NBLK, 256, 0, stream>>>(poly, mask, S);
    if (ws_size >= needWS) {
        k_stats2_mfma<<<NB2, 256, 0, stream>>>(poly, mask, Wpre, gpre, bpre, W1, S, H16);
        k_stats3_mfma<<<NB2, 256, 0, stream>>>(mask, g1, b1, W2, S, H16);
        k_out_load<<<NBO, 256, 0, stream>>>(mask, g2, b2, Wo1, bo1, Wo2, bo2, S, H16, out);
    } else {
        k_finalize_mom<<<1, 64, 0, stream>>>(Wpre, gpre, bpre, S);
        k_stats2_fb<<<NBLK, 256, 0, stream>>>(poly, mask, Wpre, W1, S);
        k_finalize<<<1, 64, 0, stream>>>(g1, b1, S, 1);
        k_rec34<false><<<NBLK, 256, 0, stream>>>(poly, mask, Wpre, W1, W2, Wo1, bo1, Wo2, bo2, S, out);
        k_finalize<<<1, 64, 0, stream>>>(g2, b2, S, 2);
        k_rec34<true><<<NBLK, 256, 0, stream>>>(poly, mask, Wpre, W1, W2, Wo1, bo1, Wo2, bo2, S, out);
    }
}

// Round 8
// 316.273 us; speedup vs baseline: 1.2994x; 1.0402x over previous
//
#include <hip/hip_runtime.h>
#include <hip/hip_bf16.h>

#define BN_TOT 24576   // B*N
#define NPTS 786432    // BN_TOT*32
#define EPS_ 1e-5f
#define NBLK 2048
#define TOTW (NBLK * 4)   // fallback path: 8192 waves
#define NB2 1024          // big-ws path: 4 blocks/CU resident when VGPR<=128
#define TOTW2 (NB2 * 4)   // 4096 waves
#define NIT2 (BN_TOT / TOTW2)  // 6 iterations per wave, exact
#define NBO 1024          // out_load: 4 blocks/CU (26KB LDS), 16 waves/CU
#define TOTWO (NBO * 4)   // 4096 waves
#define NITO (BN_TOT / TOTWO)  // 6 iterations per wave, exact

typedef float v4f __attribute__((ext_vector_type(4)));
typedef __attribute__((ext_vector_type(8))) short sv8;    // 8 bf16 (4 VGPRs)
typedef __attribute__((ext_vector_type(4))) float fv4;    // MFMA acc
typedef unsigned short u16;
typedef unsigned int u32;

__device__ __forceinline__ v4f ld4(const float* p) { return *(const v4f*)p; }
__device__ __forceinline__ void st4(float* p, v4f v) { *(v4f*)p = v; }

__device__ __forceinline__ float bf2f(u16 u) {
    union { u32 i; float f; } v; v.i = ((u32)u) << 16; return v.f;
}
// lo=a, hi=b, RNE — native HW pair conversion (v_cvt_pk_bf16_f32 via compiler)
__device__ __forceinline__ u32 pack2bf(float a, float b) {
    __hip_bfloat162 h = __float22bfloat162_rn(make_float2(a, b));
    union { __hip_bfloat162 v; u32 u; } c; c.v = h;
    return c.u;
}

// Workspace S (floats):
// [128..191] sum2 [192..255] sumsq2 [256..319] sum3 [320..383] sumsq3 [384] cnt (fallback)
// [400..444] M (x xT upper-tri 45) [445..453] sum_x (9) [454] cnt_raw
// [512+L*128 ..] scaleL/shiftL (fallback path only)
// H16 at byte offset 8192, ~100.7 MB, MFMA-NATIVE layout (u16 units per 2048-elem record):
//   value(ch, p) at  (ch>>4)*512 + (p>>4)*256 + ((ch>>2)&3)*64 + (p&15)*4 + (ch&3)
//   writer lane(quad,n) stores uint2 at mt*512 + nt*256 + lane*4 — 512B/wave contiguous.

__global__ void k_finalize(const float* __restrict__ g, const float* __restrict__ b,
                           float* __restrict__ S, int layer) {
    int c = threadIdx.x;
    if (c < 64) {
        float cnt = fmaxf(S[384], 1.f);
        float mean = S[layer * 128 + c] / cnt;
        float var = fmaxf(S[layer * 128 + 64 + c] / cnt - mean * mean, 0.f);
        float sc = g[c] * rsqrtf(var + EPS_);
        float sh = b[c] - mean * sc;
        S[512 + layer * 128 + c] = sc;
        S[512 + layer * 128 + 64 + c] = sh;
    }
}

// ---- moment-based stage-1 stats (R13-proven) -------------------------------
__global__ __launch_bounds__(256) void k_mom(const float* __restrict__ poly,
                                             const int* __restrict__ mask,
                                             float* __restrict__ S) {
    __shared__ float red[4][55];
    const int t = threadIdx.x, wv = t >> 6, lane = t & 63;
    float M[45], sx[9], cc = 0.f;
    #pragma unroll
    for (int i = 0; i < 45; i++) M[i] = 0.f;
    #pragma unroll
    for (int i = 0; i < 9; i++) sx[i] = 0.f;
    for (int idx = blockIdx.x * 256 + t; idx < NPTS; idx += NBLK * 256) {
        float m = (mask[idx] != 0) ? 1.f : 0.f;
        const float* xp = poly + (size_t)idx * 9;
        float x[9];
        #pragma unroll
        for (int j = 0; j < 9; j++) x[j] = xp[j];
        cc += m;
        int k = 0;
        #pragma unroll
        for (int a = 0; a < 9; a++) {
            float xa = x[a] * m;
            sx[a] += xa;
            #pragma unroll
            for (int b2 = a; b2 < 9; b2++) { M[k] += xa * x[b2]; k++; }
        }
    }
    #pragma unroll
    for (int i = 0; i < 45; i++) {
        float v = M[i];
        v += __shfl_xor(v, 1); v += __shfl_xor(v, 2); v += __shfl_xor(v, 4);
        v += __shfl_xor(v, 8); v += __shfl_xor(v, 16); v += __shfl_xor(v, 32);
        M[i] = v;
    }
    #pragma unroll
    for (int i = 0; i < 9; i++) {
        float v = sx[i];
        v += __shfl_xor(v, 1); v += __shfl_xor(v, 2); v += __shfl_xor(v, 4);
        v += __shfl_xor(v, 8); v += __shfl_xor(v, 16); v += __shfl_xor(v, 32);
        sx[i] = v;
    }
    {
        float v = cc;
        v += __shfl_xor(v, 1); v += __shfl_xor(v, 2); v += __shfl_xor(v, 4);
        v += __shfl_xor(v, 8); v += __shfl_xor(v, 16); v += __shfl_xor(v, 32);
        cc = v;
    }
    if (lane == 0) {
        #pragma unroll
        for (int i = 0; i < 45; i++) red[wv][i] = M[i];
        #pragma unroll
        for (int i = 0; i < 9; i++) red[wv][45 + i] = sx[i];
        red[wv][54] = cc;
    }
    __syncthreads();
    if (t < 55) atomicAdd(&S[400 + t], red[0][t] + red[1][t] + red[2][t] + red[3][t]);
}

__global__ void k_finalize_mom(const float* __restrict__ Wpre,
                               const float* __restrict__ g, const float* __restrict__ b,
                               float* __restrict__ S) {
    int c = threadIdx.x;
    if (c < 64) {
        float w[9];
        #pragma unroll
        for (int j = 0; j < 9; j++) w[j] = Wpre[c * 9 + j];
        float cnt = fmaxf(S[454], 1.f);
        float s1 = 0.f;
        #pragma unroll
        for (int j = 0; j < 9; j++) s1 += w[j] * S[445 + j];
        float s2 = 0.f;
        int k = 0;
        #pragma unroll
        for (int a = 0; a < 9; a++)
            #pragma unroll
            for (int b2 = a; b2 < 9; b2++) {
                float mm = S[400 + k];
                s2 += (a == b2) ? w[a] * w[a] * mm : 2.f * w[a] * w[b2] * mm;
                k++;
            }
        float mean = s1 / cnt;
        float var = fmaxf(s2 / cnt - mean * mean, 0.f);
        float sc = g[c] * rsqrtf(var + EPS_);
        float sh = b[c] - mean * sc;
        S[512 + c] = sc;
        S[576 + c] = sh;
        if (c == 0) S[384] = S[454];
    }
}

// ---- shared helpers --------------------------------------------------------
__device__ __forceinline__ void mm_acc(float a[4][8], v4f av, v4f w0, v4f w1) {
    #pragma unroll
    for (int i = 0; i < 4; i++) {
        #pragma unroll
        for (int j = 0; j < 4; j++) {
            a[i][j] += av[i] * w0[j];
            a[i][4 + j] += av[i] * w1[j];
        }
    }
}

__device__ __forceinline__ void tzero(float a[4][8]) {
    #pragma unroll
    for (int i = 0; i < 4; i++)
        #pragma unroll
        for (int j = 0; j < 8; j++) a[i][j] = 0.f;
}

__device__ __forceinline__ void load_x(const float* xg, float* xTw, int lane) {
    for (int e = lane; e < 288; e += 64) {
        float v = xg[e];
        int p = e / 9, c = e - 9 * p;
        xTw[c * 36 + p] = v;
    }
}

__device__ __forceinline__ void stage1(const float* xTw, const float* WpT,
                                       int pg, int cg, float a1[4][8]) {
    tzero(a1);
    #pragma unroll
    for (int k = 0; k < 9; k++) {
        v4f av = ld4(xTw + k * 36 + 4 * pg);
        v4f w0 = ld4(WpT + k * 64 + 8 * cg);
        v4f w1 = ld4(WpT + k * 64 + 8 * cg + 4);
        mm_acc(a1, av, w0, w1);
    }
}

__device__ __forceinline__ void gemv64(const float* actw, const float* WT,
                                       int pg, int cg, float a[4][8]) {
    #pragma unroll 8
    for (int k = 0; k < 64; k++) {
        v4f av = ld4(actw + k * 32 + 4 * (pg ^ (k >> 3)));
        v4f w0 = ld4(WT + k * 64 + 8 * cg);
        v4f w1 = ld4(WT + k * 64 + 8 * cg + 4);
        mm_acc(a, av, w0, w1);
    }
}

__device__ __forceinline__ void bn_store_act(float* actw, const float a[4][8],
                                             const float* sc, const float* sh,
                                             const float m[4], int pg, int cg,
                                             float f[4][8]) {
    #pragma unroll
    for (int j = 0; j < 8; j++) {
        v4f v;
        #pragma unroll
        for (int i = 0; i < 4; i++) {
            float x = fmaxf(a[i][j] * sc[j] + sh[j], 0.f) * m[i];
            v[i] = x; f[i][j] = x;
        }
        st4(actw + (8 * cg + j) * 32 + 4 * (pg ^ cg), v);
    }
}

__device__ __forceinline__ void pool_reduce(const float f[4][8], float pmax[8]) {
    #pragma unroll
    for (int j = 0; j < 8; j++) {
        float v = fmaxf(fmaxf(f[0][j], f[1][j]), fmaxf(f[2][j], f[3][j]));
        v = fmaxf(v, __shfl_xor(v, 8));
        v = fmaxf(v, __shfl_xor(v, 16));
        v = fmaxf(v, __shfl_xor(v, 32));
        pmax[j] = v;
    }
}

__device__ __forceinline__ void qa_glob(const float pmax[8], const float* W1,
                                        float* pbufw, int pg, int cg, float qa[8]) {
    if (pg == 0)
        #pragma unroll
        for (int j = 0; j < 8; j++) pbufw[8 * cg + j] = pmax[j];
    __builtin_amdgcn_wave_barrier();
    #pragma unroll
    for (int j = 0; j < 8; j++) qa[j] = 0.f;
    #pragma unroll 4
    for (int kk = 0; kk < 16; kk++) {
        float p0 = pbufw[4 * kk], p1 = pbufw[4 * kk + 1];
        float p2 = pbufw[4 * kk + 2], p3 = pbufw[4 * kk + 3];
        #pragma unroll
        for (int j = 0; j < 8; j++) {
            v4f w = ld4(W1 + (8 * cg + j) * 128 + 64 + 4 * kk);
            qa[j] += w[0] * p0 + w[1] * p1 + w[2] * p2 + w[3] * p3;
        }
    }
}

__device__ __forceinline__ void stats_acc(const float a[4][8], const float m[4],
                                          float sp[8], float ssp[8]) {
    #pragma unroll
    for (int i = 0; i < 4; i++)
        #pragma unroll
        for (int j = 0; j < 8; j++) {
            float hv = a[i][j] * m[i];
            sp[j] += hv; ssp[j] += hv * a[i][j];
        }
}

__device__ __forceinline__ void stats_flush(float sp[8], float ssp[8],
                                            float (*red_s)[64], float (*red_ss)[64],
                                            float* S, int base, int t, int wv,
                                            int pg, int cg) {
    #pragma unroll
    for (int j = 0; j < 8; j++) {
        float v = sp[j];
        v += __shfl_xor(v, 8); v += __shfl_xor(v, 16); v += __shfl_xor(v, 32);
        sp[j] = v;
        float w = ssp[j];
        w += __shfl_xor(w, 8); w += __shfl_xor(w, 16); w += __shfl_xor(w, 32);
        ssp[j] = w;
    }
    if (pg == 0)
        #pragma unroll
        for (int j = 0; j < 8; j++) { red_s[wv][8 * cg + j] = sp[j]; red_ss[wv][8 * cg + j] = ssp[j]; }
    __syncthreads();
    if (t < 64) {
        atomicAdd(&S[base + t], red_s[0][t] + red_s[1][t] + red_s[2][t] + red_s[3][t]);
        atomicAdd(&S[base + 64 + t], red_ss[0][t] + red_ss[1][t] + red_ss[2][t] + red_ss[3][t]);
    }
}

// ---- pass 2 (big ws): MFMA stage2, W1-frags in LDS, SW-pipelined (R2-proven)
// Stage2 MFMA: A=W1 (K=128), B=[feat;pooled]. Stage1 VALU in B-layout.
// Layouts (HW-validated): A[m=lane&15][k=quad*8+j], B[k=quad*8+j][n=lane&15],
// C: col(n)=lane&15, row(m)=mt*16+quad*4+r.
__global__ __launch_bounds__(256) void k_stats2_mfma(const float* __restrict__ poly,
                                                     const int* __restrict__ mask,
                                                     const float* __restrict__ Wpre,
                                                     const float* __restrict__ gpre,
                                                     const float* __restrict__ bpre,
                                                     const float* __restrict__ W1,
                                                     float* __restrict__ S,
                                                     u16* __restrict__ H16) {
    __shared__ __align__(16) float WpT[576];
    __shared__ __align__(16) float xT[4][324];
    __shared__ float scsh[128];
    __shared__ float red_s[4][64], red_ss[4][64];
    __shared__ __align__(16) uint4 awl[16 * 64];   // 16KB: W1 A-frags, lane-ordered
    const int t = threadIdx.x, wv = t >> 6, lane = t & 63;
    const int n = lane & 15, quad = lane >> 4;
    for (int i = t; i < 576; i += 256) { int c = i >> 6, ch = i & 63; WpT[i] = Wpre[ch * 9 + c]; }

    // inline BN1 finalize from moments (cold preamble)
    if (t < 64) {
        float w[9];
        #pragma unroll
        for (int j = 0; j < 9; j++) w[j] = Wpre[t * 9 + j];
        float cnt = fmaxf(S[454], 1.f);
        float s1 = 0.f;
        #pragma unroll
        for (int j = 0; j < 9; j++) s1 += w[j] * S[445 + j];
        float s2 = 0.f;
        int k = 0;
        #pragma unroll
        for (int a = 0; a < 9; a++)
            #pragma unroll
            for (int b2 = a; b2 < 9; b2++) {
                float mm = S[400 + k];
                s2 += (a == b2) ? w[a] * w[a] * mm : 2.f * w[a] * w[b2] * mm;
                k++;
            }
        float mean = s1 / cnt;
        float var = fmaxf(s2 / cnt - mean * mean, 0.f);
        float sc = gpre[t] * rsqrtf(var + EPS_);
        scsh[t] = sc;
        scsh[64 + t] = bpre[t] - mean * sc;
    }

    // build shared A-fragment table: wave wv packs mt=wv (frag depends only on lane)
    #pragma unroll
    for (int ss = 0; ss < 4; ss++) {
        const float* wr = W1 + (size_t)(wv * 16 + n) * 128 + ss * 32 + quad * 8;
        union { uint4 q; u32 w[4]; } uu;
        #pragma unroll
        for (int d = 0; d < 4; d++) uu.w[d] = pack2bf(wr[2 * d], wr[2 * d + 1]);
        awl[(wv * 4 + ss) * 64 + lane] = uu.q;
    }
    __syncthreads();
    float sck[16], shk[16];
    #pragma unroll
    for (int s = 0; s < 2; s++)
        #pragma unroll
        for (int j = 0; j < 8; j++) {
            int c = s * 32 + quad * 8 + j;
            sck[s * 8 + j] = scsh[c];
            shk[s * 8 + j] = scsh[64 + c];
        }

    float sp16[16], ssp16[16];
    #pragma unroll
    for (int e = 0; e < 16; e++) { sp16[e] = 0.f; ssp16[e] = 0.f; }

    // loop-invariant transpose-scatter addresses (e/9 hoisted out of the loop)
    int ax0, ax1, ax2, ax3, ax4;
    {
        int e = lane;        int p = e / 9; ax0 = (e - 9 * p) * 36 + p;
        e = lane + 64;       p = e / 9;     ax1 = (e - 9 * p) * 36 + p;
        e = lane + 128;      p = e / 9;     ax2 = (e - 9 * p) * 36 + p;
        e = lane + 192;      p = e / 9;     ax3 = (e - 9 * p) * 36 + p;
        e = lane + 256;      p = e / 9;     ax4 = (e - 9 * p) * 36 + p;
    }

    const sv8* awp = (const sv8*)awl;
    const int wgid = blockIdx.x * 4 + wv;
    // prologue prefetch: polyline wgid
    float xr0, xr1, xr2, xr3, xr4, mvr;
    {
        const float* xg = poly + (size_t)wgid * 288;
        xr0 = xg[lane]; xr1 = xg[lane + 64]; xr2 = xg[lane + 128]; xr3 = xg[lane + 192];
        xr4 = (lane < 32) ? xg[256 + lane] : 0.f;
        mvr = (lane < 32 && mask[wgid * 32 + lane] != 0) ? 1.f : 0.f;
    }

    for (int it = 0; it < NIT2; it++) {
        const int bn = wgid + it * TOTW2;
        const float mv = mvr;
        // scatter prefetched x into per-wave LDS tile
        xT[wv][ax0] = xr0; xT[wv][ax1] = xr1; xT[wv][ax2] = xr2; xT[wv][ax3] = xr3;
        if (lane < 32) xT[wv][ax4] = xr4;
        __builtin_amdgcn_wave_barrier();
        // issue next polyline's loads; latency hides under this iteration's compute
        if (it < NIT2 - 1) {
            const int bnn = bn + TOTW2;
            const float* xg = poly + (size_t)bnn * 288;
            xr0 = xg[lane]; xr1 = xg[lane + 64]; xr2 = xg[lane + 128]; xr3 = xg[lane + 192];
            if (lane < 32) {
                xr4 = xg[256 + lane];
                mvr = (mask[bnn * 32 + lane] != 0) ? 1.f : 0.f;
            }
        }
        // stage1 (VALU) for points {n, 16+n}, channels {s*32+quad*8+j}
        float f0[16], f1[16];
        #pragma unroll
        for (int e = 0; e < 16; e++) { f0[e] = 0.f; f1[e] = 0.f; }
        #pragma unroll
        for (int k = 0; k < 9; k++) {
            float x0 = xT[wv][k * 36 + n];
            float x1 = xT[wv][k * 36 + 16 + n];
            v4f wA0 = ld4(WpT + k * 64 + quad * 8);
            v4f wA1 = ld4(WpT + k * 64 + quad * 8 + 4);
            v4f wB0 = ld4(WpT + k * 64 + 32 + quad * 8);
            v4f wB1 = ld4(WpT + k * 64 + 32 + quad * 8 + 4);
            #pragma unroll
            for (int j = 0; j < 4; j++) {
                f0[j] += x0 * wA0[j];  f0[4 + j] += x0 * wA1[j];
                f0[8 + j] += x0 * wB0[j]; f0[12 + j] += x0 * wB1[j];
                f1[j] += x1 * wA0[j];  f1[4 + j] += x1 * wA1[j];
                f1[8 + j] += x1 * wB0[j]; f1[12 + j] += x1 * wB1[j];
            }
        }
        float mp0 = __shfl(mv, n), mp1 = __shfl(mv, 16 + n);
        #pragma unroll
        for (int e = 0; e < 16; e++) {
            f0[e] = fmaxf(f0[e] * sck[e] + shk[e], 0.f) * mp0;
            f1[e] = fmaxf(f1[e] * sck[e] + shk[e], 0.f) * mp1;
        }
        float pm[16];
        #pragma unroll
        for (int e = 0; e < 16; e++) {
            float v = fmaxf(f0[e], f1[e]);
            v = fmaxf(v, __shfl_xor(v, 1));
            v = fmaxf(v, __shfl_xor(v, 2));
            v = fmaxf(v, __shfl_xor(v, 4));
            v = fmaxf(v, __shfl_xor(v, 8));
            pm[e] = v;
        }
        sv8 bg0[2], bg1[2], bp[2];
        #pragma unroll
        for (int s = 0; s < 2; s++) {
            union { sv8 v; u32 w[4]; } a, b, c;
            #pragma unroll
            for (int d = 0; d < 4; d++) {
                a.w[d] = pack2bf(f0[s * 8 + 2 * d], f0[s * 8 + 2 * d + 1]);
                b.w[d] = pack2bf(f1[s * 8 + 2 * d], f1[s * 8 + 2 * d + 1]);
                c.w[d] = pack2bf(pm[s * 8 + 2 * d], pm[s * 8 + 2 * d + 1]);
            }
            bg0[s] = a.v; bg1[s] = b.v; bp[s] = c.v;
        }
        // per-mt MFMA: A-frags from LDS (short-lived), acc dies after stats+store
        u16* Hw = H16 + (size_t)bn * 2048;
        #pragma unroll
        for (int mt = 0; mt < 4; mt++) {
            sv8 a0 = awp[(mt * 4 + 0) * 64 + lane];
            sv8 a1 = awp[(mt * 4 + 1) * 64 + lane];
            sv8 a2 = awp[(mt * 4 + 2) * 64 + lane];
            sv8 a3 = awp[(mt * 4 + 3) * 64 + lane];
            fv4 c0 = {0.f, 0.f, 0.f, 0.f}, c1 = {0.f, 0.f, 0.f, 0.f};
            c0 = __builtin_amdgcn_mfma_f32_16x16x32_bf16(a0, bg0[0], c0, 0, 0, 0);
            c0 = __builtin_amdgcn_mfma_f32_16x16x32_bf16(a1, bg0[1], c0, 0, 0, 0);
            c0 = __builtin_amdgcn_mfma_f32_16x16x32_bf16(a2, bp[0], c0, 0, 0, 0);
            c0 = __builtin_amdgcn_mfma_f32_16x16x32_bf16(a3, bp[1], c0, 0, 0, 0);
            c1 = __builtin_amdgcn_mfma_f32_16x16x32_bf16(a0, bg1[0], c1, 0, 0, 0);
            c1 = __builtin_amdgcn_mfma_f32_16x16x32_bf16(a1, bg1[1], c1, 0, 0, 0);
            c1 = __builtin_amdgcn_mfma_f32_16x16x32_bf16(a2, bp[0], c1, 0, 0, 0);
            c1 = __builtin_amdgcn_mfma_f32_16x16x32_bf16(a3, bp[1], c1, 0, 0, 0);
            #pragma unroll
            for (int r = 0; r < 4; r++) {
                sp16[mt * 4 + r] += c0[r] * mp0 + c1[r] * mp1;
                ssp16[mt * 4 + r] += c0[r] * c0[r] * mp0 + c1[r] * c1[r] * mp1;
            }
            uint2 pk0, pk1;
            pk0.x = pack2bf(c0[0], c0[1]); pk0.y = pack2bf(c0[2], c0[3]);
            pk1.x = pack2bf(c1[0], c1[1]); pk1.y = pack2bf(c1[2], c1[3]);
            *(uint2*)(Hw + mt * 512 + lane * 4) = pk0;
            *(uint2*)(Hw + mt * 512 + 256 + lane * 4) = pk1;
        }
        __builtin_amdgcn_wave_barrier();
    }
    #pragma unroll
    for (int e = 0; e < 16; e++) {
        float v = sp16[e];
        v += __shfl_xor(v, 1); v += __shfl_xor(v, 2); v += __shfl_xor(v, 4); v += __shfl_xor(v, 8);
        sp16[e] = v;
        float w = ssp16[e];
        w += __shfl_xor(w, 1); w += __shfl_xor(w, 2); w += __shfl_xor(w, 4); w += __shfl_xor(w, 8);
        ssp16[e] = w;
    }
    if (n == 0) {
        #pragma unroll
        for (int mt = 0; mt < 4; mt++)
            #pragma unroll
            for (int r = 0; r < 4; r++) {
                red_s[wv][mt * 16 + quad * 4 + r] = sp16[mt * 4 + r];
                red_ss[wv][mt * 16 + quad * 4 + r] = ssp16[mt * 4 + r];
            }
    }
    __syncthreads();
    if (t < 64) {
        atomicAdd(&S[128 + t], red_s[0][t] + red_s[1][t] + red_s[2][t] + red_s[3][t]);
        atomicAdd(&S[128 + 64 + t], red_ss[0][t] + red_ss[1][t] + red_ss[2][t] + red_ss[3][t]);
    }
}

// ---- pass 3 (big ws): MFMA-native H16 in/out, W2-frags in LDS --------------
__global__ __launch_bounds__(256) void k_stats3_mfma(const int* __restrict__ mask,
                                                     const float* __restrict__ g1,
                                                     const float* __restrict__ b1,
                                                     const float* __restrict__ W2,
                                                     float* __restrict__ S,
                                                     u16* __restrict__ H16) {
    __shared__ float scsh[128];
    __shared__ float red_s[4][64], red_ss[4][64];
    __shared__ __align__(16) uint4 awl[8 * 64];   // 8KB: W2 A-frags, lane-ordered
    const int t = threadIdx.x, wv = t >> 6, lane = t & 63;
    const int n = lane & 15, quad = lane >> 4;

    if (t < 64) {
        float cnt = fmaxf(S[454], 1.f);
        float mean = S[128 + t] / cnt;
        float var = fmaxf(S[192 + t] / cnt - mean * mean, 0.f);
        float sc = g1[t] * rsqrtf(var + EPS_);
        scsh[t] = sc;
        scsh[64 + t] = b1[t] - mean * sc;
    }

    #pragma unroll
    for (int s = 0; s < 2; s++) {
        const float* wr = W2 + (wv * 16 + n) * 64 + s * 32 + quad * 8;
        union { uint4 q; u32 w[4]; } uu;
        #pragma unroll
        for (int d = 0; d < 4; d++) uu.w[d] = pack2bf(wr[2 * d], wr[2 * d + 1]);
        awl[(wv * 2 + s) * 64 + lane] = uu.q;
    }
    __syncthreads();
    float sck[16], shk[16];
    #pragma unroll
    for (int s = 0; s < 2; s++)
        #pragma unroll
        for (int j = 0; j < 8; j++) {
            int k = s * 32 + quad * 8 + j;
            sck[s * 8 + j] = scsh[k];
            shk[s * 8 + j] = scsh[64 + k];
        }

    float sp16[16], ssp16[16];
    #pragma unroll
    for (int e = 0; e < 16; e++) { sp16[e] = 0.f; ssp16[e] = 0.f; }

    const sv8* awp = (const sv8*)awl;
    const int wgid = blockIdx.x * 4 + wv;
    // reader offset for B-fragment gather: ch = s*32+quad*8+j ->
    //   mt' = s*2+(quad>>1), quad'_base = (quad&1)*2 (+ j>>2), r = j&3
    const int hoff = (quad >> 1) * 512 + (quad & 1) * 128 + n * 4;
    uint2 hr[2][2][2];   // [nt][s][half]
    float mvr;
    {
        const u16* Hb = H16 + (size_t)wgid * 2048;
        #pragma unroll
        for (int nt = 0; nt < 2; nt++)
            #pragma unroll
            for (int s = 0; s < 2; s++)
                #pragma unroll
                for (int h = 0; h < 2; h++)
                    hr[nt][s][h] = *(const uint2*)(Hb + hoff + s * 1024 + nt * 256 + h * 64);
        mvr = (lane < 32 && mask[wgid * 32 + lane] != 0) ? 1.f : 0.f;
    }

    for (int it = 0; it < NIT2; it++) {
        const int bn = wgid + it * TOTW2;
        const float mv = mvr;
        float mpn[2] = {__shfl(mv, n), __shfl(mv, 16 + n)};
        sv8 bg[2][2];
        #pragma unroll
        for (int nt = 0; nt < 2; nt++)
            #pragma unroll
            for (int s = 0; s < 2; s++) {
                u32 ws[4] = {hr[nt][s][0].x, hr[nt][s][0].y, hr[nt][s][1].x, hr[nt][s][1].y};
                union { sv8 v; u32 w[4]; } uu;
                #pragma unroll
                for (int d = 0; d < 4; d++) {
                    union { u32 u; float f; } lo, hi;
                    lo.u = ws[d] << 16; hi.u = ws[d] & 0xFFFF0000u;
                    float g0 = fmaxf(lo.f * sck[s * 8 + 2 * d] + shk[s * 8 + 2 * d], 0.f) * mpn[nt];
                    float g1v = fmaxf(hi.f * sck[s * 8 + 2 * d + 1] + shk[s * 8 + 2 * d + 1], 0.f) * mpn[nt];
                    uu.w[d] = pack2bf(g0, g1v);
                }
                bg[nt][s] = uu.v;
            }
        // prefetch next polyline's h1 fragments (hr fully consumed above)
        if (it < NIT2 - 1) {
            const int bnn = bn + TOTW2;
            const u16* Hb = H16 + (size_t)bnn * 2048;
            #pragma unroll
            for (int nt = 0; nt < 2; nt++)
                #pragma unroll
                for (int s = 0; s < 2; s++)
                    #pragma unroll
                    for (int h = 0; h < 2; h++)
                        hr[nt][s][h] = *(const uint2*)(Hb + hoff + s * 1024 + nt * 256 + h * 64);
            if (lane < 32) mvr = (mask[bnn * 32 + lane] != 0) ? 1.f : 0.f;
        }
        u16* Hw = H16 + (size_t)bn * 2048;
        #pragma unroll
        for (int nt = 0; nt < 2; nt++) {
            float mp = mpn[nt];
            #pragma unroll
            for (int mt = 0; mt < 4; mt++) {
                sv8 a0 = awp[(mt * 2 + 0) * 64 + lane];
                sv8 a1 = awp[(mt * 2 + 1) * 64 + lane];
                fv4 c = {0.f, 0.f, 0.f, 0.f};
                c = __builtin_amdgcn_mfma_f32_16x16x32_bf16(a0, bg[nt][0], c, 0, 0, 0);
                c = __builtin_amdgcn_mfma_f32_16x16x32_bf16(a1, bg[nt][1], c, 0, 0, 0);
                #pragma unroll
                for (int r = 0; r < 4; r++) {
                    sp16[mt * 4 + r] += c[r] * mp;
                    ssp16[mt * 4 + r] += c[r] * c[r] * mp;
                }
                uint2 pk;
                pk.x = pack2bf(c[0], c[1]);
                pk.y = pack2bf(c[2], c[3]);
                *(uint2*)(Hw + mt * 512 + nt * 256 + lane * 4) = pk;
            }
        }
    }
    #pragma unroll
    for (int e = 0; e < 16; e++) {
        float v = sp16[e];
        v += __shfl_xor(v, 1); v += __shfl_xor(v, 2); v += __shfl_xor(v, 4); v += __shfl_xor(v, 8);
        sp16[e] = v;
        float w = ssp16[e];
        w += __shfl_xor(w, 1); w += __shfl_xor(w, 2); w += __shfl_xor(w, 4); w += __shfl_xor(w, 8);
        ssp16[e] = w;
    }
    if (n == 0) {
        #pragma unroll
        for (int mt = 0; mt < 4; mt++)
            #pragma unroll
            for (int r = 0; r < 4; r++) {
                red_s[wv][mt * 16 + quad * 4 + r] = sp16[mt * 4 + r];
                red_ss[wv][mt * 16 + quad * 4 + r] = ssp16[mt * 4 + r];
            }
    }
    __syncthreads();
    if (t < 64) {
        atomicAdd(&S[256 + t], red_s[0][t] + red_s[1][t] + red_s[2][t] + red_s[3][t]);
        atomicAdd(&S[256 + 64 + t], red_ss[0][t] + red_ss[1][t] + red_ss[2][t] + red_ss[3][t]);
    }
}

// ---- pass 4 (big ws): H16 read + bf16-packed Wo1/Wo2 in LDS (26KB, 4 blk/CU)
__global__ __launch_bounds__(256) void k_out_load(const int* __restrict__ mask,
                                                  const float* __restrict__ g2,
                                                  const float* __restrict__ b2,
                                                  const float* __restrict__ Wo1,
                                                  const float* __restrict__ bo1,
                                                  const float* __restrict__ Wo2,
                                                  const float* __restrict__ bo2,
                                                  const float* __restrict__ S,
                                                  const u16* __restrict__ H16,
                                                  float* __restrict__ out) {
    __shared__ __align__(16) u32 Wo1p[2048];   // 8KB:  [kk*64+ch]  = bf16(w[2kk],w[2kk+1])
    __shared__ __align__(16) u32 Wo2p[4096];   // 16KB: [kk*128+o] = bf16(w[2kk],w[2kk+1])
    __shared__ float pbuf[4][64];
    __shared__ float scsh[128];
    const int t = threadIdx.x, wv = t >> 6, lane = t & 63;
    const int n = lane & 15, quad = lane >> 4;
    if (t < 64) {
        float cnt = fmaxf(S[454], 1.f);
        float mean = S[256 + t] / cnt;
        float var = fmaxf(S[320 + t] / cnt - mean * mean, 0.f);
        float sc = g2[t] * rsqrtf(var + EPS_);
        scsh[t] = sc;
        scsh[64 + t] = b2[t] - mean * sc;
    }
    for (int i = t; i < 2048; i += 256) {
        int kk = i >> 6, ch = i & 63;
        Wo1p[i] = pack2bf(Wo1[ch * 64 + 2 * kk], Wo1[ch * 64 + 2 * kk + 1]);
    }
    for (int i = t; i < 4096; i += 256) {
        int kk = i >> 7, o = i & 127;
        Wo2p[i] = pack2bf(Wo2[o * 64 + 2 * kk], Wo2[o * 64 + 2 * kk + 1]);
    }
    __syncthreads();
    float sc3[16], sh3[16];
    #pragma unroll
    for (int mt = 0; mt < 4; mt++)
        #pragma unroll
        for (int r = 0; r < 4; r++) {
            sc3[mt * 4 + r] = scsh[mt * 16 + quad * 4 + r];
            sh3[mt * 4 + r] = scsh[64 + mt * 16 + quad * 4 + r];
        }
    float bo1v = bo1[lane], bo2a = bo2[lane], bo2b = bo2[64 + lane];
    const int wgid = blockIdx.x * 4 + wv;
    uint2 hr[4][2];   // [mt][nt]
    float mvr;
    {
        const u16* Hb = H16 + (size_t)wgid * 2048;
        #pragma unroll
        for (int mt = 0; mt < 4; mt++)
            #pragma unroll
            for (int nt = 0; nt < 2; nt++)
                hr[mt][nt] = *(const uint2*)(Hb + mt * 512 + nt * 256 + lane * 4);
        mvr = (lane < 32 && mask[wgid * 32 + lane] != 0) ? 1.f : 0.f;
    }
    for (int it = 0; it < NITO; it++) {
        const int bn = wgid + it * TOTWO;
        const float mv = mvr;
        float mpn[2] = {__shfl(mv, n), __shfl(mv, 16 + n)};
        float vf = __ballot(mv > 0.5f) ? 1.f : 0.f;
        float pm[16];
        #pragma unroll
        for (int mt = 0; mt < 4; mt++)
            #pragma unroll
            for (int nt = 0; nt < 2; nt++) {
                u32 wx = hr[mt][nt].x, wy = hr[mt][nt].y;
                float v0 = bf2f((u16)(wx & 0xFFFFu)), v1 = bf2f((u16)(wx >> 16));
                float v2 = bf2f((u16)(wy & 0xFFFFu)), v3 = bf2f((u16)(wy >> 16));
                float mp = mpn[nt];
                float e0 = fmaxf(v0 * sc3[mt * 4 + 0] + sh3[mt * 4 + 0], 0.f) * mp;
                float e1 = fmaxf(v1 * sc3[mt * 4 + 1] + sh3[mt * 4 + 1], 0.f) * mp;
                float e2 = fmaxf(v2 * sc3[mt * 4 + 2] + sh3[mt * 4 + 2], 0.f) * mp;
                float e3 = fmaxf(v3 * sc3[mt * 4 + 3] + sh3[mt * 4 + 3], 0.f) * mp;
                if (nt == 0) {
                    pm[mt * 4 + 0] = e0; pm[mt * 4 + 1] = e1;
                    pm[mt * 4 + 2] = e2; pm[mt * 4 + 3] = e3;
                } else {
                    pm[mt * 4 + 0] = fmaxf(pm[mt * 4 + 0], e0);
                    pm[mt * 4 + 1] = fmaxf(pm[mt * 4 + 1], e1);
                    pm[mt * 4 + 2] = fmaxf(pm[mt * 4 + 2], e2);
                    pm[mt * 4 + 3] = fmaxf(pm[mt * 4 + 3], e3);
                }
            }
        if (it < NITO - 1) {
            const int bnn = bn + TOTWO;
            const u16* Hb = H16 + (size_t)bnn * 2048;
            #pragma unroll
            for (int mt = 0; mt < 4; mt++)
                #pragma unroll
                for (int nt = 0; nt < 2; nt++)
                    hr[mt][nt] = *(const uint2*)(Hb + mt * 512 + nt * 256 + lane * 4);
            if (lane < 32) mvr = (mask[bnn * 32 + lane] != 0) ? 1.f : 0.f;
        }
        #pragma unroll
        for (int e = 0; e < 16; e++) {
            float v = pm[e];
            v = fmaxf(v, __shfl_xor(v, 1));
            v = fmaxf(v, __shfl_xor(v, 2));
            v = fmaxf(v, __shfl_xor(v, 4));
            v = fmaxf(v, __shfl_xor(v, 8));
            pm[e] = v;
        }
        if (n == 0) {
            #pragma unroll
            for (int mt = 0; mt < 4; mt++)
                #pragma unroll
                for (int r = 0; r < 4; r++)
                    pbuf[wv][mt * 16 + quad * 4 + r] = pm[mt * 4 + r];
        }
        __builtin_amdgcn_wave_barrier();
        float y1 = bo1v;
        #pragma unroll 8
        for (int kk = 0; kk < 32; kk++) {
            u32 w = Wo1p[kk * 64 + lane];
            union { u32 u; float f; } lo, hi;
            lo.u = w << 16; hi.u = w & 0xFFFF0000u;
            y1 += lo.f * pbuf[wv][2 * kk] + hi.f * pbuf[wv][2 * kk + 1];
        }
        y1 = fmaxf(y1, 0.f);
        pbuf[wv][lane] = y1;
        __builtin_amdgcn_wave_barrier();
        float o0 = bo2a, o1 = bo2b;
        #pragma unroll 8
        for (int kk = 0; kk < 32; kk++) {
            float p0 = pbuf[wv][2 * kk], p1 = pbuf[wv][2 * kk + 1];
            u32 wa = Wo2p[kk * 128 + lane];
            u32 wb = Wo2p[kk * 128 + 64 + lane];
            union { u32 u; float f; } la, ha, lb, hb;
            la.u = wa << 16; ha.u = wa & 0xFFFF0000u;
            lb.u = wb << 16; hb.u = wb & 0xFFFF0000u;
            o0 += la.f * p0 + ha.f * p1;
            o1 += lb.f * p0 + hb.f * p1;
        }
        out[(size_t)bn * 128 + lane] = o0 * vf;
        out[(size_t)bn * 128 + 64 + lane] = o1 * vf;
        __builtin_amdgcn_wave_barrier();
    }
}

// ---- fallback (small ws): recompute path, untouched ------------------------
__device__ __forceinline__ void qa_lds_fb(const float pmax[8], const float* W1pT,
                                          int cg, float qa[8]) {
    #pragma unroll
    for (int j = 0; j < 8; j++) qa[j] = 0.f;
    #pragma unroll
    for (int k = 0; k < 64; k++) {
        float pv = __shfl(pmax[k & 7], k >> 3);
        v4f w0 = ld4(W1pT + k * 64 + 8 * cg);
        v4f w1 = ld4(W1pT + k * 64 + 8 * cg + 4);
        #pragma unroll
        for (int j = 0; j < 4; j++) { qa[j] += pv * w0[j]; qa[4 + j] += pv * w1[j]; }
    }
}

__global__ __launch_bounds__(256) void k_stats2_fb(const float* __restrict__ poly,
                                                   const int* __restrict__ mask,
                                                   const float* __restrict__ Wpre,
                                                   const float* __restrict__ W1,
                                                   float* __restrict__ S) {
    __shared__ __align__(16) float WpT[576];
    __shared__ __align__(16) float W1aT[4096];
    __shared__ __align__(16) float W1pT[4096];
    __shared__ __align__(16) float act[4][2048];
    __shared__ __align__(16) float xT[4][324];
    __shared__ float red_s[4][64], red_ss[4][64];
    const int t = threadIdx.x, wv = t >> 6, lane = t & 63;
    const int pg = lane >> 3, cg = lane & 7;
    for (int i = t; i < 576; i += 256) { int c = i >> 6, ch = i & 63; WpT[i] = Wpre[ch * 9 + c]; }
    for (int i = t; i < 4096; i += 256) {
        int k = i >> 6, ch = i & 63;
        W1aT[i] = W1[ch * 128 + k];
        W1pT[i] = W1[ch * 128 + 64 + k];
    }
    __syncthreads();
    float sc1[8], sh1[8];
    #pragma unroll
    for (int j = 0; j < 8; j++) { sc1[j] = S[512 + 8 * cg + j]; sh1[j] = S[576 + 8 * cg + j]; }
    float sp[8] = {0}, ssp[8] = {0};
    const int wgid = blockIdx.x * 4 + wv;
    for (int bn = wgid; bn < BN_TOT; bn += TOTW) {
        float mv = (lane < 32 && mask[bn * 32 + lane] != 0) ? 1.f : 0.f;
        float m[4];
        #pragma unroll
        for (int i = 0; i < 4; i++) m[i] = __shfl(mv, 4 * pg + i);
        load_x(poly + (size_t)bn * 288, xT[wv], lane);
        __builtin_amdgcn_wave_barrier();
        float a1[4][8], f[4][8];
        stage1(xT[wv], WpT, pg, cg, a1);
        bn_store_act(act[wv], a1, sc1, sh1, m, pg, cg, f);
        float pmax[8], qa[8];
        pool_reduce(f, pmax);
        qa_lds_fb(pmax, W1pT, cg, qa);
        __builtin_amdgcn_wave_barrier();
        float a2[4][8];
        #pragma unroll
        for (int i = 0; i < 4; i++)
            #pragma unroll
            for (int j = 0; j < 8; j++) a2[i][j] = qa[j];
        gemv64(act[wv], W1aT, pg, cg, a2);
        stats_acc(a2, m, sp, ssp);
        __builtin_amdgcn_wave_barrier();
    }
    stats_flush(sp, ssp, red_s, red_ss, S, 128, t, wv, pg, cg);
}

template<bool DO_OUT>
__global__ __launch_bounds__(256) void k_rec34(const float* __restrict__ poly,
                                               const int* __restrict__ mask,
                                               const float* __restrict__ Wpre,
                                               const float* __restrict__ W1,
                                               const float* __restrict__ W2,
                                               const float* __restrict__ Wo1,
                                               const float* __restrict__ bo1,
                                               const float* __restrict__ Wo2,
                                               const float* __restrict__ bo2,
                                               float* __restrict__ S,
                                               float* __restrict__ out) {
    __shared__ __align__(16) float WpT[576];
    __shared__ __align__(16) float W1aT[4096];
    __shared__ __align__(16) float W2T[4096];
    __shared__ __align__(16) float act[4][2048];
    __shared__ __align__(16) float xT[4][324];
    __shared__ float pbuf[4][64];
    __shared__ float red_s[4][64], red_ss[4][64];
    const int t = threadIdx.x, wv = t >> 6, lane = t & 63;
    const int pg = lane >> 3, cg = lane & 7;
    for (int i = t; i < 576; i += 256) { int c = i >> 6, ch = i & 63; WpT[i] = Wpre[ch * 9 + c]; }
    for (int i = t; i < 4096; i += 256) {
        int k = i >> 6, ch = i & 63;
        W1aT[i] = W1[ch * 128 + k];
        W2T[i] = W2[ch * 64 + k];
    }
    __syncthreads();
    float sc1[8], sh1[8], sc2[8], sh2[8], sc3[8], sh3[8];
    #pragma unroll
    for (int j = 0; j < 8; j++) {
        sc1[j] = S[512 + 8 * cg + j]; sh1[j] = S[576 + 8 * cg + j];
        sc2[j] = S[640 + 8 * cg + j]; sh2[j] = S[704 + 8 * cg + j];
    }
    if constexpr (DO_OUT)
        #pragma unroll
        for (int j = 0; j < 8; j++) { sc3[j] = S[768 + 8 * cg + j]; sh3[j] = S[832 + 8 * cg + j]; }
    float bo1v = 0.f, bo2a = 0.f, bo2b = 0.f;
    if constexpr (DO_OUT) { bo1v = bo1[lane]; bo2a = bo2[lane]; bo2b = bo2[64 + lane]; }
    float sp[8] = {0}, ssp[8] = {0};
    const int wgid = blockIdx.x * 4 + wv;
    for (int bn = wgid; bn < BN_TOT; bn += TOTW) {
        float mv = (lane < 32 && mask[bn * 32 + lane] != 0) ? 1.f : 0.f;
        float m[4];
        #pragma unroll
        for (int i = 0; i < 4; i++) m[i] = __shfl(mv, 4 * pg + i);
        load_x(poly + (size_t)bn * 288, xT[wv], lane);
        __builtin_amdgcn_wave_barrier();
        float a1[4][8], f[4][8];
        stage1(xT[wv], WpT, pg, cg, a1);
        bn_store_act(act[wv], a1, sc1, sh1, m, pg, cg, f);
        float pmax[8], qa[8];
        pool_reduce(f, pmax);
        qa_glob(pmax, W1, pbuf[wv], pg, cg, qa);
        __builtin_amdgcn_wave_barrier();
        float a2[4][8];
        #pragma unroll
        for (int i = 0; i < 4; i++)
            #pragma unroll
            for (int j = 0; j < 8; j++) a2[i][j] = qa[j];
        gemv64(act[wv], W1aT, pg, cg, a2);
        __builtin_amdgcn_wave_barrier();
        bn_store_act(act[wv], a2, sc2, sh2, m, pg, cg, f);
        __builtin_amdgcn_wave_barrier();
        float a3[4][8];
        tzero(a3);
        gemv64(act[wv], W2T, pg, cg, a3);
        if constexpr (!DO_OUT) {
            stats_acc(a3, m, sp, ssp);
        } else {
            float px[8];
            #pragma unroll
            for (int j = 0; j < 8; j++) {
                float v = 0.f;
                #pragma unroll
                for (int i = 0; i < 4; i++)
                    v = fmaxf(v, fmaxf(a3[i][j] * sc3[j] + sh3[j], 0.f) * m[i]);
                px[j] = v;
            }
            #pragma unroll
            for (int j = 0; j < 8; j++) {
                float v = px[j];
                v = fmaxf(v, __shfl_xor(v, 8));
                v = fmaxf(v, __shfl_xor(v, 16));
                v = fmaxf(v, __shfl_xor(v, 32));
                px[j] = v;
            }
            if (pg == 0)
                #pragma unroll
                for (int j = 0; j < 8; j++) pbuf[wv][8 * cg + j] = px[j];
            __builtin_amdgcn_wave_barrier();
            float y1 = bo1v;
            #pragma unroll 4
            for (int kk = 0; kk < 16; kk++) {
                v4f w = ld4(Wo1 + lane * 64 + 4 * kk);
                y1 += w[0] * pbuf[wv][4 * kk] + w[1] * pbuf[wv][4 * kk + 1]
                    + w[2] * pbuf[wv][4 * kk + 2] + w[3] * pbuf[wv][4 * kk + 3];
            }
            y1 = fmaxf(y1, 0.f);
            pbuf[wv][lane] = y1;
            __builtin_amdgcn_wave_barrier();
            float o0 = bo2a, o1 = bo2b;
            #pragma unroll 4
            for (int kk = 0; kk < 16; kk++) {
                v4f w0 = ld4(Wo2 + lane * 64 + 4 * kk);
                v4f w1 = ld4(Wo2 + (64 + lane) * 64 + 4 * kk);
                float p0 = pbuf[wv][4 * kk], p1 = pbuf[wv][4 * kk + 1];
                float p2 = pbuf[wv][4 * kk + 2], p3 = pbuf[wv][4 * kk + 3];
                o0 += w0[0] * p0 + w0[1] * p1 + w0[2] * p2 + w0[3] * p3;
                o1 += w1[0] * p0 + w1[1] * p1 + w1[2] * p2 + w1[3] * p3;
            }
            float vf = __ballot(mv > 0.5f) ? 1.f : 0.f;
            out[(size_t)bn * 128 + lane] = o0 * vf;
            out[(size_t)bn * 128 + 64 + lane] = o1 * vf;
        }
        __builtin_amdgcn_wave_barrier();
    }
    if constexpr (!DO_OUT)
        stats_flush(sp, ssp, red_s, red_ss, S, 256, t, wv, pg, cg);
}

extern "C" void kernel_launch(void* const* d_in, const int* in_sizes, int n_in,
                              void* d_out, int out_size, void* d_ws, size_t ws_size,
                              hipStream_t stream) {
    const float* poly = (const float*)d_in[0];
    const int*   mask = (const int*)d_in[1];
    const float* Wpre = (const float*)d_in[2];
    const float* gpre = (const float*)d_in[3];
    const float* bpre = (const float*)d_in[4];
    const float* W1   = (const float*)d_in[5];
    const float* g1   = (const float*)d_in[6];
    const float* b1   = (const float*)d_in[7];
    const float* W2   = (const float*)d_in[8];
    const float* g2   = (const float*)d_in[9];
    const float* b2   = (const float*)d_in[10];
    const float* Wo1  = (const float*)d_in[11];
    const float* bo1  = (const float*)d_in[12];
    const float* Wo2  = (const float*)d_in[13];
    const float* bo2  = (const float*)d_in[14];

    float* S = (float*)d_ws;
    u16* H16 = (u16*)((char*)d_ws + 8192);
    float* out = (float*)d_out;

    const size_t needWS = 8192 + (size_t)BN_TOT * 2048 * sizeof(u16);  // ~100.7 MB

    hipMemsetAsync(S, 0, 512 * sizeof(float), stream);
    k_mom<<<NBLK, 256, 0, stream>>>(poly, mask, S);
    if (ws_size >= needWS) {
        k_stats2_mfma<<<NB2, 256, 0, stream>>>(poly, mask, Wpre, gpre, bpre, W1, S, H16);
        k_stats3_mfma<<<NB2, 256, 0, stream>>>(mask, g1, b1, W2, S, H16);
        k_out_load<<<NBO, 256, 0, stream>>>(mask, g2, b2, Wo1, bo1, Wo2, bo2, S, H16, out);
    } else {
        k_finalize_mom<<<1, 64, 0, stream>>>(Wpre, gpre, bpre, S);
        k_stats2_fb<<<NBLK, 256, 0, stream>>>(poly, mask, Wpre, W1, S);
        k_finalize<<<1, 64, 0, stream>>>(g1, b1, S, 1);
        k_rec34<false><<<NBLK, 256, 0, stream>>>(poly, mask, Wpre, W1, W2, Wo1, bo1, Wo2, bo2, S, out);
        k_finalize<<<1, 64, 0, stream>>>(g2, b2, S, 2);
        k_rec34<true><<<NBLK, 256, 0, stream>>>(poly, mask, Wpre, W1, W2, Wo1, bo1, Wo2, bo2, S, out);
    }
}